// Round 22
// baseline (1514.525 us; speedup 1.0000x reference)
//
#include <hip/hip_runtime.h>
#include <math.h>

#define NB 8
#define NC 192
#define DIN 384
#define NL 3136
#define ROWS (NB*NL)     // 25088
#define NE 6160
#define NHID 768

typedef unsigned short u16;
typedef unsigned int u32;
typedef unsigned long long u64;
typedef __attribute__((ext_vector_type(8))) short bh8;
typedef __attribute__((ext_vector_type(4))) float f4;

typedef __attribute__((address_space(1))) const void gl_as1;
typedef __attribute__((address_space(3))) void gl_as3;
#define GL16(g, l) __builtin_amdgcn_global_load_lds((gl_as1*)(const void*)(g), (gl_as3*)(void*)(l), 16, 0, 0)

// ---------- helpers ----------
__device__ __forceinline__ float wredsum(float v){
  v += __shfl_xor(v, 1, 64); v += __shfl_xor(v, 2, 64); v += __shfl_xor(v, 4, 64);
  v += __shfl_xor(v, 8, 64); v += __shfl_xor(v, 16, 64); v += __shfl_xor(v, 32, 64);
  return v;
}
__device__ __forceinline__ void edge_decode(int e, int& u, int& v){
  if (e < 3080){ int h = e/55, w = e - h*55; u = h*56 + w; v = u + 1; }
  else { int e2 = e - 3080; int h = e2/56, w = e2 - h*56; u = h*56 + w; v = u + 56; }
}
__device__ __forceinline__ float siluf(float x){ return x / (1.0f + expf(-x)); }
__device__ __forceinline__ float sofplus(float x){ return fmaxf(x, 0.0f) + log1pf(expf(-fabsf(x))); }
__device__ __forceinline__ float geluf(float x){ return 0.5f * x * (1.0f + erff(x * 0.70710678118654752f)); }
__device__ __forceinline__ u16 f2bf(float x){
  u32 u = __float_as_uint(x);
  u32 r = (u + 0x7fffu + ((u >> 16) & 1u)) >> 16;
  return (u16)r;
}
__device__ __forceinline__ float bf2f(u16 h){ return __uint_as_float(((u32)h) << 16); }

// ---------- fused: ln1 || keys || wprep (block ranges) ----------
__global__ __launch_bounds__(256) void keysln_kernel(const float* __restrict__ x,
    const float* __restrict__ g, const float* __restrict__ bt,
    u16* __restrict__ lnout, u64* __restrict__ keys,
    const float* __restrict__ ipw, const float* __restrict__ opw,
    const float* __restrict__ f1w, const float* __restrict__ f2w,
    u16* __restrict__ ipo, u16* __restrict__ opo, u16* __restrict__ f1o, u16* __restrict__ f2o){
  int bid = blockIdx.x;
  int lane = threadIdx.x & 63;
  if (bid < 6272){
    int gw = (int)((bid * 256u + threadIdx.x) >> 6);
    const float* r = x + (size_t)gw * NC;
    float v[3]; float s = 0.f;
#pragma unroll
    for (int j = 0; j < 3; ++j){ v[j] = r[lane + 64*j]; s += v[j]; }
    s = wredsum(s);
    float mu = s * (1.0f / NC);
    float q = 0.f;
#pragma unroll
    for (int j = 0; j < 3; ++j){ float dd = v[j] - mu; q += dd*dd; }
    q = wredsum(q);
    float rs = rsqrtf(q * (1.0f / NC) + 1e-5f);
    u16* o = lnout + (size_t)gw * NC;
#pragma unroll
    for (int j = 0; j < 3; ++j){
      int dch = lane + 64*j;
      o[dch] = f2bf((v[j] - mu) * rs * g[dch] + bt[dch]);
    }
  } else if (bid < 18592){
    int gw = (int)(((bid - 6272) * 256u + threadIdx.x) >> 6);
    if (gw >= NB * NE) return;
    int b = gw / NE, e = gw - b * NE;
    int u, v; edge_decode(e, u, v);
    const float* ru = x + ((size_t)b * NL + u) * NC;
    const float* rv = x + ((size_t)b * NL + v) * NC;
    float s = 0.f, su = 0.f, sv = 0.f;
#pragma unroll
    for (int j = 0; j < 3; ++j){
      float a = ru[lane + 64*j], c = rv[lane + 64*j];
      s += a * c; su += a * a; sv += c * c;
    }
    s = wredsum(s);
    su = wredsum(su);
    sv = wredsum(sv);
    if (lane == 0){
      float nu = sqrtf(su) + 1e-8f;
      float nv = sqrtf(sv) + 1e-8f;
      float cosv = s / (nu * nv);
      float wgt = expf(1.0f - cosv);
      keys[(size_t)b*NE + e] = ((u64)__float_as_uint(wgt) << 32) | (u64)(u32)e;
    }
  } else {
    int wb = bid - 18592;
    const float* W; u16* o; int K; int nk; int base;
    if (wb < 576){ W = ipw; o = ipo; K = 192; nk = 768*192; base = wb; }
    else if (wb < 864){ W = opw; o = opo; K = 384; nk = 192*384; base = wb - 576; }
    else if (wb < 1440){ W = f1w; o = f1o; K = 192; nk = 768*192; base = wb - 864; }
    else { W = f2w; o = f2o; K = 768; nk = 192*768; base = wb - 1440; }
    int i = base*256 + threadIdx.x;
    if (i >= nk) return;
    int r = i / K, c = i - r*K;
    float v = W[i];
    u16 hi = f2bf(v);
    o[(size_t)r * 2 * K + c] = hi;
    o[(size_t)r * 2 * K + K + c] = f2bf(v - bf2f(hi));
  }
}

// ---------- tree body (256 threads): Boruvka + adjl4 + atomic-free single-wave BFS ----------
__device__ void tree_body(char* sm, int b, const u64* __restrict__ keys_g,
      int* __restrict__ order_g, int* __restrict__ parpos_g, int* __restrict__ pos_g,
      int* __restrict__ lvl_g, int* __restrict__ nlev_g){
  const int t = threadIdx.x;
  const int NT = 256;
  u64* best   = (u64*)sm;            // [3136]
  u16* parent = (u16*)(sm + 25088);
  u16* comp   = (u16*)(sm + 31360);
  u16* mstU   = (u16*)(sm + 37632);
  u16* mstV   = (u16*)(sm + 43904);
  u32* cnts   = (u32*)(sm + 56448);
  u16* adjl4  = (u16*)sm;            // [3136*4] (over best)
  u32* deg    = (u32*)(sm + 25088);  // (over parent+comp)
  u32* fr     = (u32*)(sm + 37632);  // (over mstU+mstV): node | pnode<<16
  u16* ppos   = (u16*)(sm + 50176);

  const u64* kb = keys_g + (size_t)b * NE;
  for (int v = t; v < NL; v += NT) parent[v] = (u16)v;
  if (t == 0){ cnts[0] = 0; cnts[3] = 0xffffffffu; }
  __syncthreads();

  u32 gpass = 0;
  for (int round = 0; round < 24; ++round){
    for (int it = 0; it < 12; ++it){
      bool ch = false;
      for (int c0 = 0; c0 < NL; c0 += NT*4){
        int vv[4]; u16 pv[4]; int nb2 = 0;
#pragma unroll
        for (int j = 0; j < 4; ++j){ int v = c0 + t + j*NT; if (v < NL){ vv[nb2] = v; pv[nb2] = parent[v]; ++nb2; } }
        u16 gp[4];
        for (int j = 0; j < nb2; ++j) gp[j] = parent[pv[j]];
        for (int j = 0; j < nb2; ++j){ if (gp[j] != pv[j]){ parent[vv[j]] = gp[j]; ch = true; } }
      }
      bool docheck = (it & 1);
      if (docheck && ch) cnts[3] = gpass;
      __syncthreads();
      if (docheck){
        u32 seen = cnts[3];
        __syncthreads();
        u32 cur = gpass; ++gpass;
        if (seen != cur) break;
      }
    }
    for (int v = t; v < NL; v += NT){ comp[v] = parent[v]; best[v] = ~0ull; }
    if (t == 0) cnts[2] = 0;
    __syncthreads();
    for (int c0 = 0; c0 < NE; c0 += NT*8){
      int ee[8]; int eu[8], ev[8]; u16 cu[8], cv[8]; u64 kk[8]; int nb2 = 0;
#pragma unroll
      for (int j = 0; j < 8; ++j){
        int e = c0 + t + j*NT;
        if (e < NE){ ee[nb2] = e; int u, v; edge_decode(e, u, v); eu[nb2] = u; ev[nb2] = v; ++nb2; }
      }
      for (int j = 0; j < nb2; ++j){ cu[j] = comp[eu[j]]; cv[j] = comp[ev[j]]; }
      for (int j = 0; j < nb2; ++j){ kk[j] = kb[ee[j]]; }
      for (int j = 0; j < nb2; ++j){
        if (cu[j] != cv[j]){
          atomicMin(&best[cu[j]], kk[j]);
          atomicMin(&best[cv[j]], kk[j]);
        }
      }
    }
    __syncthreads();
    for (int c0 = 0; c0 < NL; c0 += NT*4){
      int rr[4]; u64 bk[4]; int nb2 = 0;
#pragma unroll
      for (int j = 0; j < 4; ++j){ int r = c0 + t + j*NT; if (r < NL){ rr[nb2] = r; ++nb2; } }
      u16 cr[4];
      for (int j = 0; j < nb2; ++j) cr[j] = comp[rr[j]];
      for (int j = 0; j < nb2; ++j) bk[j] = (cr[j] == (u16)rr[j]) ? best[rr[j]] : ~0ull;
      int uu[4], vv2[4]; u16 ru2[4], rv2[4];
      for (int j = 0; j < nb2; ++j){
        if (bk[j] != ~0ull){ int e = (int)(u32)bk[j]; edge_decode(e, uu[j], vv2[j]); }
      }
      for (int j = 0; j < nb2; ++j){
        if (bk[j] != ~0ull){ ru2[j] = comp[uu[j]]; rv2[j] = comp[vv2[j]]; }
      }
      for (int j = 0; j < nb2; ++j){
        if (bk[j] != ~0ull){
          int r = rr[j];
          u16 other = (ru2[j] == (u16)r) ? rv2[j] : ru2[j];
          bool mutual = (best[other] == bk[j]);
          if (!mutual || (u16)r < other){
            parent[r] = other;
            u32 id = atomicAdd(&cnts[0], 1);
            mstU[id] = (u16)uu[j]; mstV[id] = (u16)vv2[j];
            cnts[2] = 1;
          }
        }
      }
    }
    __syncthreads();
    if (cnts[0] >= (u32)(NL - 1) || cnts[2] == 0) break;
  }
  __syncthreads();

  const int nm = NL - 1;
  for (int v = t; v < NL; v += NT){
    deg[v] = 0;
    *(u64*)&adjl4[v*4] = 0xffffffffffffffffull;
  }
  __syncthreads();
  for (int c0 = 0; c0 < nm; c0 += NT*4){
    int uu[4], vv2[4]; int nb2 = 0;
#pragma unroll
    for (int j = 0; j < 4; ++j){
      int i = c0 + t + j*NT;
      if (i < nm){ uu[nb2] = mstU[i]; vv2[nb2] = mstV[i]; ++nb2; }
    }
    for (int j = 0; j < nb2; ++j){
      u32 s1 = atomicAdd(&deg[uu[j]], 1); adjl4[uu[j]*4 + s1] = (u16)vv2[j];
      u32 s2 = atomicAdd(&deg[vv2[j]], 1); adjl4[vv2[j]*4 + s2] = (u16)uu[j];
    }
  }
  __syncthreads();

  if (t == 0){
    fr[0] = 0u | (0xffffu << 16);
    ppos[0] = 0;
    lvl_g[b*3200 + 0] = 0; lvl_g[b*3200 + 1] = 1;
  }
  __syncthreads();

  // ---- atomic-free single-wave BFS: wave-scan allocation, per-level waitcnt,
  // fr prefetch one window ahead (level frontier region is immutable within a level).
  if (t < 64){
    int flo = 0, fhi = 1, d = 1;
    int total = 1;
    while (fhi < NL){
      u32 fcur = (flo + t < fhi) ? fr[flo + t] : 0;
      for (int base2 = flo; base2 < fhi; base2 += 64){
        int idx = base2 + t;
        bool act = idx < fhi;
        u32 fnext = 0;
        if (base2 + 64 + t < fhi) fnext = fr[base2 + 64 + t];
        int u = (int)(fcur & 0xffffu), pn = (int)(fcur >> 16);
        u64 four = act ? *(const u64*)&adjl4[u*4] : 0xffffffffffffffffull;
        int vj[4], keep[4];
#pragma unroll
        for (int j = 0; j < 4; ++j){
          int v = (int)((four >> (16*j)) & 0xffffu);
          vj[j] = v;
          keep[j] = (act && v != 0xffff && v != pn) ? 1 : 0;
        }
        int nc = keep[0] + keep[1] + keep[2] + keep[3];
        int inc = nc;
#pragma unroll
        for (int off = 1; off < 64; off <<= 1){
          int sh = __shfl_up(inc, off, 64);
          if (t >= off) inc += sh;
        }
        int excl = total + inc - nc;
        int o1 = keep[0], o2 = keep[0] + keep[1], o3 = keep[0] + keep[1] + keep[2];
        if (keep[0]){ fr[excl]      = (u32)vj[0] | ((u32)u << 16); ppos[excl]      = (u16)idx; }
        if (keep[1]){ fr[excl + o1] = (u32)vj[1] | ((u32)u << 16); ppos[excl + o1] = (u16)idx; }
        if (keep[2]){ fr[excl + o2] = (u32)vj[2] | ((u32)u << 16); ppos[excl + o2] = (u16)idx; }
        if (keep[3]){ fr[excl + o3] = (u32)vj[3] | ((u32)u << 16); ppos[excl + o3] = (u16)idx; }
        total = total + __shfl(inc, 63, 64);
        fcur = fnext;
      }
      if (t == 0) lvl_g[b*3200 + d + 1] = total;
      flo = fhi; fhi = total; ++d;
      asm volatile("s_waitcnt lgkmcnt(0)" ::: "memory");
      if (fhi == flo) break;
    }
    if (t == 0) nlev_g[b] = d;
  }
  __syncthreads();

  for (int p = t; p < NL; p += NT){
    u32 f = fr[p];
    int node = (int)(f & 0xffffu);
    order_g[b*NL + p] = node;
    parpos_g[b*NL + p] = (int)ppos[p];
    pos_g[b*NL + node] = p;
  }
}

// ---------- in_proj GEMM body (BN=128, DUALOUT), LDS passed in ----------
__device__ void inproj_body(char* sm, int bid, const u16* __restrict__ Ap, const u16* __restrict__ Wp,
                            float* __restrict__ Cm, float* __restrict__ C2){
  const int K = 192, K2 = 384;
  short* Ah = (short*)sm;              // 128*64
  short* Wh = (short*)(sm + 16384);    // 128*64
  short* Wl = (short*)(sm + 32768);    // 128*64
  const int bn = (bid % 6) * 128, bm = (bid / 6) * 128;
  const int tid = threadIdx.x, lane = tid & 63, wid = tid >> 6;
  const int wr = wid >> 1, wc = wid & 1;
  f4 acc[4][4];
#pragma unroll
  for (int mf = 0; mf < 4; ++mf)
#pragma unroll
    for (int nf = 0; nf < 4; ++nf) acc[mf][nf] = (f4){0.f,0.f,0.f,0.f};

  for (int k0 = 0; k0 < K; k0 += 64){
#pragma unroll
    for (int j = 0; j < 4; ++j){
      int isb = wid*4 + j;
      int r = isb*8 + (lane >> 3);
      int c = lane & 7;
      const u16* src = Ap + (size_t)(bm + r) * K + k0 + ((c ^ (r & 7)) << 3);
      GL16(src, &Ah[isb*512]);
    }
#pragma unroll
    for (int j = 0; j < 4; ++j){
      int isb = wid*4 + j;
      int r = isb*8 + (lane >> 3);
      int c = lane & 7;
      const u16* src = Wp + (size_t)(bn + r) * K2 + k0 + ((c ^ (r & 7)) << 3);
      GL16(src,     &Wh[isb*512]);
      GL16(src + K, &Wl[isb*512]);
    }
    __syncthreads();
#pragma unroll
    for (int kk = 0; kk < 2; ++kk){
      bh8 whf[4], wlf[4], ahf[4];
#pragma unroll
      for (int nf = 0; nf < 4; ++nf){
        int rw = wc*64 + nf*16 + (lane & 15);
        int c = kk*4 + (lane >> 4);
        int ad = rw*64 + ((c ^ (rw & 7)) * 8);
        whf[nf] = *(const bh8*)&Wh[ad];
        wlf[nf] = *(const bh8*)&Wl[ad];
      }
#pragma unroll
      for (int mf = 0; mf < 4; ++mf){
        int ra = wr*64 + mf*16 + (lane & 15);
        int c = kk*4 + (lane >> 4);
        int ad = ra*64 + ((c ^ (ra & 7)) * 8);
        ahf[mf] = *(const bh8*)&Ah[ad];
      }
#pragma unroll
      for (int mf = 0; mf < 4; ++mf)
#pragma unroll
        for (int nf = 0; nf < 4; ++nf){
          acc[mf][nf] = __builtin_amdgcn_mfma_f32_16x16x32_bf16(ahf[mf], whf[nf], acc[mf][nf], 0, 0, 0);
          acc[mf][nf] = __builtin_amdgcn_mfma_f32_16x16x32_bf16(ahf[mf], wlf[nf], acc[mf][nf], 0, 0, 0);
        }
    }
    __syncthreads();
  }
  const int cb = bn + wc*64;
#pragma unroll
  for (int mf = 0; mf < 4; ++mf){
    int row = bm + wr*64 + mf*16 + (lane >> 4)*4;
#pragma unroll
    for (int nf = 0; nf < 4; ++nf){
      int col = cb + nf*16 + (lane & 15);
#pragma unroll
      for (int r = 0; r < 4; ++r){
        float v = acc[mf][nf][r];
        float* op = (col < 384) ? Cm : C2;
        int oc = (col < 384) ? col : col - 384;
        op[(size_t)(row + r) * 384 + oc] = v;
      }
    }
  }
}

// ---------- fused: blocks 0..7 = tree, blocks 8.. = in_proj GEMM ----------
__global__ __launch_bounds__(256) void fused_tree_inproj(
    const u64* __restrict__ keysg, int* __restrict__ ordg, int* __restrict__ ppg,
    int* __restrict__ posg, int* __restrict__ lvlg, int* __restrict__ nlvg,
    const u16* __restrict__ Ap, const u16* __restrict__ Wp,
    float* __restrict__ Cm, float* __restrict__ C2){
  __shared__ __align__(16) char sm[62736];
  int bid = blockIdx.x;
  if (bid < 8){
    tree_body(sm, bid, keysg, ordg, ppg, posg, lvlg, nlvg);
  } else {
    inproj_body(sm, bid - 8, Ap, Wp, Cm, C2);
  }
}

// ---------- fused: blocks 0..7 = window-schedule build, blocks 8.. = conv ----------
__global__ __launch_bounds__(256) void sched_conv_kernel(
    const int* __restrict__ lvl_g, const int* __restrict__ nlev_g,
    u32* __restrict__ wsched_g, int* __restrict__ nwin_g,
    const float* __restrict__ xs, const float* __restrict__ cw,
    const float* __restrict__ cb, float* __restrict__ u){
  __shared__ int lvls[3200];
  int bid = blockIdx.x;
  if (bid < 8){
    int b = bid;
    int tid = threadIdx.x;
    int d = nlev_g[b];
    for (int i = tid; i <= d; i += 256) lvls[i] = lvl_g[b*3200 + i];
    __syncthreads();
    if (tid >= 64) return;
    int lane = tid;
    u32* su = wsched_g + (size_t)b*6528;
    u32* sd = su + 3264;
    int nk = d - 1;
    for (int pass = 0; pass < 2; ++pass){
      u32* out = pass ? sd : su;
      int carry = 0;
      for (int c0 = 0; c0 < nk; c0 += 64){
        int kk = c0 + lane;
        bool valid = kk < nk;
        int lo = 0, hi = 0, wc = 0;
        if (valid){
          int dd = pass ? (1 + kk) : (d - 1 - kk);
          lo = lvls[dd]; hi = lvls[dd+1];
          wc = (hi - lo + 63) >> 6;
        }
        int inc = wc;
        for (int off = 1; off < 64; off <<= 1){
          int v = __shfl_up(inc, off, 64);
          if (lane >= off) inc += v;
        }
        int excl = carry + inc - wc;
        if (valid){
          for (int w = 0; w < wc; ++w){
            int base2 = lo + (w << 6);
            u32 e = (u32)base2 | ((u32)hi << 16);
            if (base2 + 64 >= hi) e |= 0x80000000u;
            out[excl + w] = e;
          }
        }
        carry += __shfl(inc, 63, 64);
      }
      if (lane == 0) nwin_g[b*2 + pass] = carry;
    }
  } else {
    int idx = (bid - 8) * 256 + threadIdx.x;
    if (idx >= ROWS * 96) return;
    int q = idx % 96; int l = idx / 96;
    int b = l / NL; int hw = l - b * NL; int h = hw / 56; int wcc = hw - h * 56;
    int c4 = q * 4;
    float4 acc = *(const float4*)(cb + c4);
#pragma unroll
    for (int kh = 0; kh < 3; ++kh){
      int hh = h + kh - 1; if (hh < 0 || hh >= 56) continue;
#pragma unroll
      for (int kw = 0; kw < 3; ++kw){
        int wwc = wcc + kw - 1; if (wwc < 0 || wwc >= 56) continue;
        float4 iv = *(const float4*)(xs + ((size_t)(b * NL + hh*56 + wwc)) * DIN + c4);
        float4 wv = *(const float4*)(cw + (size_t)(kh*3 + kw) * DIN + c4);
        acc.x += iv.x * wv.x; acc.y += iv.y * wv.y; acc.z += iv.z * wv.z; acc.w += iv.w * wv.w;
      }
    }
    float4 o; o.x = siluf(acc.x); o.y = siluf(acc.y); o.z = siluf(acc.z); o.w = siluf(acc.w);
    *(float4*)(u + (size_t)l * DIN + c4) = o;
  }
}

// ---------- layernorm (wave per row); BF16OUT -> plain bf16 row ----------
template<int D, bool BF16OUT>
__global__ __launch_bounds__(256) void ln_kernel(const float* __restrict__ in, const float* __restrict__ g,
                                                 const float* __restrict__ bt, void* __restrict__ outv){
  int gw = (int)((blockIdx.x * 256u + threadIdx.x) >> 6);
  int lane = threadIdx.x & 63;
  if (gw >= ROWS) return;
  constexpr int J = D / 64;
  const float* r = in + (size_t)gw * D;
  float v[J]; float s = 0.f;
#pragma unroll
  for (int j = 0; j < J; ++j){ v[j] = r[lane + 64*j]; s += v[j]; }
  s = wredsum(s);
  float mu = s * (1.0f / D);
  float q = 0.f;
#pragma unroll
  for (int j = 0; j < J; ++j){ float dd = v[j] - mu; q += dd*dd; }
  q = wredsum(q);
  float rs = rsqrtf(q * (1.0f / D) + 1e-5f);
  if (BF16OUT){
    u16* o = (u16*)outv + (size_t)gw * D;
#pragma unroll
    for (int j = 0; j < J; ++j){
      int dch = lane + 64*j;
      float y = (v[j] - mu) * rs * g[dch] + bt[dch];
      o[dch] = f2bf(y);
    }
  } else {
    float* o = (float*)outv + (size_t)gw * D;
#pragma unroll
    for (int j = 0; j < J; ++j){ int dch = lane + 64*j; o[dch] = (v[j] - mu) * rs * g[dch] + bt[dch]; }
  }
}

// ---------- MFMA GEMM: A plain bf16 [M,K]; W split hi|lo [N,2K]. ----------
template<int BN, bool BIAS, int ACT, bool RESID, bool OBF16, bool DUALOUT>
__global__ __launch_bounds__(256) void mgemm_kernel(
    const u16* __restrict__ Ap, const u16* __restrict__ Wp,
    const float* __restrict__ bias, const float* __restrict__ resid,
    float* __restrict__ Cm, float* __restrict__ C2, int M, int N, int K){
  static_assert(BN == 64 || BN == 128, "BN");
  constexpr int WT = (BN == 128) ? 64 : 32;
  constexpr int NF = WT / 16;
  __shared__ short Ah[128*64];
  __shared__ short Wh[BN*64], Wl[BN*64];
  const int bm = blockIdx.y * 128, bn = blockIdx.x * BN;
  const int tid = threadIdx.x, lane = tid & 63, wid = tid >> 6;
  const int wr = wid >> 1, wc = wid & 1;
  const int K2 = 2 * K;
  f4 acc[4][NF];
#pragma unroll
  for (int mf = 0; mf < 4; ++mf)
#pragma unroll
    for (int nf = 0; nf < NF; ++nf) acc[mf][nf] = (f4){0.f,0.f,0.f,0.f};

  for (int k0 = 0; k0 < K; k0 += 64){
#pragma unroll
    for (int j = 0; j < 4; ++j){
      int isb = wid*4 + j;
      int r = isb*8 + (lane >> 3);
      int c = lane & 7;
      const u16* src = Ap + (size_t)(bm + r) * K + k0 + ((c ^ (r & 7)) << 3);
      GL16(src, &Ah[isb*512]);
    }
#pragma unroll
    for (int j = 0; j < BN/32; ++j){
      int isb = wid*(BN/32) + j;
      int r = isb*8 + (lane >> 3);
      int c = lane & 7;
      const u16* src = Wp + (size_t)(bn + r) * K2 + k0 + ((c ^ (r & 7)) << 3);
      GL16(src,     &Wh[isb*512]);
      GL16(src + K, &Wl[isb*512]);
    }
    __syncthreads();
#pragma unroll
    for (int kk = 0; kk < 2; ++kk){
      bh8 whf[NF], wlf[NF], ahf[4];
#pragma unroll
      for (int nf = 0; nf < NF; ++nf){
        int rw = wc*WT + nf*16 + (lane & 15);
        int c = kk*4 + (lane >> 4);
        int ad = rw*64 + ((c ^ (rw & 7)) * 8);
        whf[nf] = *(const bh8*)&Wh[ad];
        wlf[nf] = *(const bh8*)&Wl[ad];
      }
#pragma unroll
      for (int mf = 0; mf < 4; ++mf){
        int ra = wr*64 + mf*16 + (lane & 15);
        int c = kk*4 + (lane >> 4);
        int ad = ra*64 + ((c ^ (ra & 7)) * 8);
        ahf[mf] = *(const bh8*)&Ah[ad];
      }
#pragma unroll
      for (int mf = 0; mf < 4; ++mf)
#pragma unroll
        for (int nf = 0; nf < NF; ++nf){
          acc[mf][nf] = __builtin_amdgcn_mfma_f32_16x16x32_bf16(ahf[mf], whf[nf], acc[mf][nf], 0, 0, 0);
          acc[mf][nf] = __builtin_amdgcn_mfma_f32_16x16x32_bf16(ahf[mf], wlf[nf], acc[mf][nf], 0, 0, 0);
        }
    }
    __syncthreads();
  }
  const int cb = bn + wc*WT;
#pragma unroll
  for (int mf = 0; mf < 4; ++mf){
    int row = bm + wr*64 + mf*16 + (lane >> 4)*4;
#pragma unroll
    for (int nf = 0; nf < NF; ++nf){
      int col = cb + nf*16 + (lane & 15);
#pragma unroll
      for (int r = 0; r < 4; ++r){
        float v = acc[mf][nf][r];
        if (BIAS) v += bias[col];
        if (ACT == 1) v = geluf(v);
        if (RESID) v += resid[(size_t)(row + r) * N + col];
        if (DUALOUT){
          float* op = (col < 384) ? Cm : C2;
          int oc = (col < 384) ? col : col - 384;
          op[(size_t)(row + r) * 384 + oc] = v;
        } else if (OBF16){
          u16* op = (u16*)Cm;
          op[(size_t)(row + r) * N + col] = f2bf(v);
        } else {
          Cm[(size_t)(row + r) * N + col] = v;
        }
      }
    }
  }
}

// ---------- x_proj + dt_proj + softplus + w/feat (wave per row), BFS-pos output ----------
__global__ __launch_bounds__(256) void xdbl_kernel(const float* __restrict__ u,
    const float* __restrict__ xpw, const float* __restrict__ dtw_g,
    const float* __restrict__ dtb, const float* __restrict__ alog, const int* __restrict__ pos_g,
    float* __restrict__ wout, float* __restrict__ fout, float* __restrict__ csout){
  __shared__ float xw[14*384];
  __shared__ float dw[384*12];
  __shared__ float db[384];
  __shared__ float An[384];
  int t = threadIdx.x;
  for (int i = t; i < 14*384; i += 256) xw[i] = xpw[i];
  for (int i = t; i < 384*12; i += 256) dw[i] = dtw_g[i];
  for (int i = t; i < 384; i += 256){ db[i] = dtb[i]; An[i] = -expf(alog[i]); }
  __syncthreads();
  int wave = t >> 6, lane = t & 63;
  int row0 = blockIdx.x * 16 + wave * 4;
  for (int rr = 0; rr < 4; ++rr){
    int m = row0 + rr;
    int b = m / NL;
    int pos = pos_g[m];
    size_t orow = ((size_t)b * NL + pos) * DIN;
    const float* ur = u + (size_t)m * DIN;
    float u6[6];
#pragma unroll
    for (int j = 0; j < 6; ++j) u6[j] = ur[lane + 64*j];
    float xd[14];
#pragma unroll
    for (int r = 0; r < 14; ++r){
      float p = 0.f;
#pragma unroll
      for (int j = 0; j < 6; ++j) p += u6[j] * xw[r*384 + lane + 64*j];
      xd[r] = wredsum(p);
    }
    float Bs = xd[12], Cv = xd[13];
#pragma unroll
    for (int j = 0; j < 6; ++j){
      int dch = lane + 64*j;
      float pre = db[dch];
#pragma unroll
      for (int r = 0; r < 12; ++r) pre += xd[r] * dw[dch*12 + r];
      float dts = sofplus(pre);
      float wv = expf(dts * An[dch]);
      float fv = dts * Bs * u6[j];
      wout[orow + dch] = wv;
      fout[orow + dch] = fv;
    }
    if (lane == 0) csout[m] = Cv;
  }
}

// ---------- w transpose: [b][pos][384] -> planar [b][ch][pos] (64x64 LDS tiles) ----------
__global__ __launch_bounds__(256) void wtr_kernel(const float* __restrict__ in, float* __restrict__ out){
  __shared__ float tile[64][65];
  int blk = blockIdx.x;
  int b = blk / (49*6);
  int r = blk - b*(49*6);
  int pt = r / 6, ct = r - pt*6;
  int t = threadIdx.x;
  int tr = t >> 6, lane = t & 63;
  const float* src = in + ((size_t)b*NL + (size_t)pt*64) * DIN + ct*64;
#pragma unroll
  for (int k = 0; k < 16; ++k){
    int rr = tr + k*4;
    tile[rr][lane] = src[(size_t)rr*DIN + lane];
  }
  __syncthreads();
  float* dst = out + ((size_t)b*DIN + (size_t)ct*64) * NL + (size_t)pt*64;
#pragma unroll
  for (int k = 0; k < 16; ++k){
    int cc = tr + k*4;
    dst[(size_t)cc*NL + lane] = tile[lane][cc];
  }
}

// ---------- sweep8: flat window schedule + depth-2 w/pp prefetch. ----------
template<bool UP>
__device__ __forceinline__ void sweep_run(const u32* __restrict__ sc, int nw,
    float* __restrict__ Sp, const float* __restrict__ wbase, const int* __restrict__ pg, int lane){
  if (nw <= 0) return;
  u32 d0 = sc[lane];
  u32 d1 = sc[64 + lane];
  int curch = 0;
  float wA = 0.f, wB = 0.f; int pA = 0, pB = 0;
  int baseA = 0, hiA = 0, baseB = 0, hiB = 0;
  u32 eA = 0, eB = 0; bool aA = false, aB = false;
  {
    u32 dc = __shfl(d0, 0, 64);
    baseA = (int)(dc & 0xffffu); hiA = (int)((dc >> 16) & 0x7fffu); eA = dc >> 31;
    int p = baseA + lane; aA = p < hiA;
    if (aA){ wA = wbase[p]; pA = pg[p]; }
  }
  if (nw > 1){
    u32 dc = __shfl(d0, 1, 64);
    baseB = (int)(dc & 0xffffu); hiB = (int)((dc >> 16) & 0x7fffu); eB = dc >> 31;
    int p = baseB + lane; aB = p < hiB;
    if (aB){ wB = wbase[p]; pB = pg[p]; }
  }
  for (int iw = 0; iw < nw; ++iw){
    int ch = iw >> 6;
    if (ch != curch){ d0 = d1; d1 = sc[(ch + 1)*64 + lane]; curch = ch; }
    float wN = 0.f; int pN = 0; int baseN = 0, hiN = 0; u32 eN = 0; bool aN = false;
    int iw2 = iw + 2;
    if (iw2 < nw){
      int ch2 = iw2 >> 6;
      u32 dc2 = __shfl((ch2 == curch) ? d0 : d1, iw2 & 63, 64);
      baseN = (int)(dc2 & 0xffffu); hiN = (int)((dc2 >> 16) & 0x7fffu); eN = dc2 >> 31;
      int p = baseN + lane; aN = p < hiN;
      if (aN){ wN = wbase[p]; pN = pg[p]; }
    }
    int p = baseA + lane;
    if (aA){
      if (UP){
        float s = Sp[p];
        atomicAdd(&Sp[pA], wA * s);
      } else {
        float s = Sp[p]; float h = Sp[pA];
        Sp[p] = s + wA * (h - wA * s);
      }
    }
    if (eA){
      asm volatile("s_waitcnt lgkmcnt(0)" ::: "memory");
    }
    baseA = baseB; hiA = hiB; aA = aB; wA = wB; pA = pB; eA = eB;
    baseB = baseN; hiB = hiN; aB = aN; wB = wN; pB = pN; eB = eN;
  }
}

__global__ __launch_bounds__(256) void sweep8_kernel(const float* __restrict__ featp, const float* __restrict__ wtr,
    float* __restrict__ Hp, const int* __restrict__ parpos_g,
    const u32* __restrict__ wsched_g, const int* __restrict__ nwin_g){
  __shared__ float S[4*NL];    // 50176B -> 3 blocks/CU
  int blk = blockIdx.x;
  int b = blk & 7, q = blk >> 3;   // tree b pinned to XCD b
  int t = threadIdx.x, lane = t & 63, wv = t >> 6;
  const int* pg = parpos_g + b*NL;
  const float* fbase = featp + (size_t)b*NL*DIN + q*4;
  const float* wbase = wtr + ((size_t)b*DIN + q*4 + wv) * NL;
  float*       hbase = Hp    + (size_t)b*NL*DIN + q*4;
  for (int i = t; i < NL; i += 256){
    float4 f = *(const float4*)(fbase + (size_t)i*DIN);
    S[0*NL + i] = f.x; S[1*NL + i] = f.y; S[2*NL + i] = f.z; S[3*NL + i] = f.w;
  }
  __syncthreads();
  float* Sp = &S[wv*NL];

  const u32* su = wsched_g + (size_t)b*6528;
  const u32* sd = su + 3264;
  int nwu = nwin_g[b*2], nwd = nwin_g[b*2 + 1];
  sweep_run<true>(su, nwu, Sp, wbase, pg, lane);
  sweep_run<false>(sd, nwd, Sp, wbase, pg, lane);

  __syncthreads();
  for (int i = t; i < NL; i += 256){
    float4 o;
    o.x = S[0*NL + i]; o.y = S[1*NL + i]; o.z = S[2*NL + i]; o.w = S[3*NL + i];
    *(float4*)(hbase + (size_t)i*DIN) = o;
  }
}

// ---------- y = Cs*H + Ds*u -> LN -> * silu(z) -> plain bf16 (pos-row input) ----------
__global__ __launch_bounds__(256) void ynorm_kernel(const float* __restrict__ Hp, const float* __restrict__ u,
    const float* __restrict__ z, const float* __restrict__ Cs, const int* __restrict__ order_g,
    const float* __restrict__ Ds, const float* __restrict__ g, const float* __restrict__ bt,
    u16* __restrict__ out){
  int gw = (int)((blockIdx.x * 256u + threadIdx.x) >> 6);   // pos-row
  int lane = threadIdx.x & 63;
  if (gw >= ROWS) return;
  int b = gw / NL;
  int node = order_g[gw];
  size_t nrow = (size_t)b * NL + node;
  float Cv = Cs[nrow];
  const float* hr = Hp + (size_t)gw * DIN;
  const float* ur = u + nrow * DIN;
  const float* zr = z + nrow * DIN;
  float y[6]; float s = 0.f;
#pragma unroll
  for (int j = 0; j < 6; ++j){
    int dch = lane + 64*j;
    y[j] = Cv * hr[dch] + Ds[dch] * ur[dch];
    s += y[j];
  }
  s = wredsum(s);
  float mu = s * (1.0f / DIN);
  float q = 0.f;
#pragma unroll
  for (int j = 0; j < 6; ++j){ float dd = y[j] - mu; q += dd*dd; }
  q = wredsum(q);
  float rs = rsqrtf(q * (1.0f / DIN) + 1e-5f);
  u16* o = out + nrow * DIN;
#pragma unroll
  for (int j = 0; j < 6; ++j){
    int dch = lane + 64*j;
    float yn = (y[j] - mu) * rs * g[dch] + bt[dch];
    float v = yn * siluf(zr[dch]);
    o[dch] = f2bf(v);
  }
}

// ---------- host orchestration ----------
extern "C" void kernel_launch(void* const* d_in, const int* in_sizes, int n_in,
                              void* d_out, int out_size, void* d_ws, size_t ws_size,
                              hipStream_t stream){
  const float* x_in       = (const float*)d_in[0];
  const float* norm1_w    = (const float*)d_in[1];
  const float* norm1_b    = (const float*)d_in[2];
  const float* in_proj_w  = (const float*)d_in[3];
  const float* conv_w     = (const float*)d_in[4];
  const float* conv_b     = (const float*)d_in[5];
  const float* x_proj_w   = (const float*)d_in[6];
  const float* dt_proj_w  = (const float*)d_in[7];
  const float* dt_proj_b  = (const float*)d_in[8];
  const float* A_log      = (const float*)d_in[9];
  const float* Ds         = (const float*)d_in[10];
  const float* out_norm_w = (const float*)d_in[11];
  const float* out_norm_b = (const float*)d_in[12];
  const float* out_proj_w = (const float*)d_in[13];
  const float* norm2_w    = (const float*)d_in[14];
  const float* norm2_b    = (const float*)d_in[15];
  const float* fc1_w      = (const float*)d_in[16];
  const float* fc1_b      = (const float*)d_in[17];
  const float* fc2_w      = (const float*)d_in[18];
  const float* fc2_b      = (const float*)d_in[19];
  const float* fnorm_w    = (const float*)d_in[20];
  const float* fnorm_b    = (const float*)d_in[21];

  float* ws = (float*)d_ws;
  float* X     = ws + 0;
  u16*   bufAh = (u16*)(ws + 4816896);
  float* bufZ  = ws + 9633792;
  float* bufW  = ws + 19267584;
  float* bufU  = ws + 28901376;
  float* bufF  = ws + 38535168;
  u16*   Gp    = (u16*)bufU;
  float* Csb   = ws + 48168960;
  int*   ordg  = (int*)(ws + 48194048);
  int*   ppg   = (int*)(ws + 48219136);
  int*   lvlg  = (int*)(ws + 48244224);
  int*   nlvg  = (int*)(ws + 48269824);
  u64*   keysg = (u64*)(ws + 48269832);
  u16*   ipWp  = (u16*)(ws + 48393480);
  u16*   opWp  = (u16*)(ws + 48540936);
  u16*   fc1Wp = (u16*)(ws + 48614664);
  u16*   fc2Wp = (u16*)(ws + 48762120);
  int*   posg  = (int*)(ws + 48909576);
  float* wtrp  = ws + 48934664;          // planar w [b][384][NL]
  u32*   wschg = (u32*)(ws + 58568456);  // 8*6528 u32
  int*   nwing = (int*)(ws + 58620680);  // 16 ints

  hipMemcpyAsync(X, x_in, (size_t)ROWS * NC * sizeof(float), hipMemcpyDeviceToDevice, stream);

  for (int i = 0; i < 2; ++i){
    // ln1 (0..6271) || keys (6272..18591) || wprep (18592..20607)
    keysln_kernel<<<20608, 256, 0, stream>>>(X, norm1_w + i*NC, norm1_b + i*NC, bufAh, keysg,
                                             in_proj_w + (size_t)i*NHID*NC, out_proj_w + (size_t)i*NC*DIN,
                                             fc1_w + (size_t)i*NHID*NC, fc2_w + (size_t)i*NC*NHID,
                                             ipWp, opWp, fc1Wp, fc2Wp);

    // fused: tree (blocks 0..7) + in_proj GEMM (blocks 8..1183)
    fused_tree_inproj<<<8 + 6*196, 256, 0, stream>>>(keysg, ordg, ppg, posg, lvlg, nlvg,
                                                     bufAh, ipWp, bufF, bufZ);

    // sched (blocks 0..7) || conv (blocks 8..9415)
    sched_conv_kernel<<<8 + (ROWS*96)/256, 256, 0, stream>>>(lvlg, nlvg, wschg, nwing,
                                                             bufF, conv_w + (size_t)i*9*DIN, conv_b + i*DIN, bufU);

    xdbl_kernel<<<ROWS/16, 256, 0, stream>>>(bufU, x_proj_w + (size_t)i*14*DIN, dt_proj_w + (size_t)i*DIN*12,
                                             dt_proj_b + i*DIN, A_log + i*DIN, posg, bufW, bufF, Csb);

    wtr_kernel<<<8*49*6, 256, 0, stream>>>(bufW, wtrp);

    sweep8_kernel<<<NB*96, 256, 0, stream>>>(bufF, wtrp, bufF, ppg, wschg, nwing);

    ynorm_kernel<<<ROWS/4, 256, 0, stream>>>(bufF, bufU, bufZ, Csb, ordg, Ds + i*DIN,
                                             out_norm_w + i*DIN, out_norm_b + i*DIN, (u16*)bufW);

    mgemm_kernel<64,false,0,true,false,false><<<dim3(3,196), 256, 0, stream>>>((u16*)bufW, opWp, nullptr, X, X, nullptr, ROWS, 192, 384);

    ln_kernel<192,true><<<ROWS/4, 256, 0, stream>>>(X, norm2_w + i*NC, norm2_b + i*NC, bufAh);
    mgemm_kernel<128,true,1,false,true,false><<<dim3(6,196), 256, 0, stream>>>(bufAh, fc1Wp, fc1_b + i*NHID, nullptr, (float*)Gp, nullptr, ROWS, NHID, 192);
    mgemm_kernel<64,true,0,true,false,false><<<dim3(3,196), 256, 0, stream>>>(Gp, fc2Wp, fc2_b + i*NC, X, X, nullptr, ROWS, 192, 768);
  }

  ln_kernel<192,false><<<ROWS/4, 256, 0, stream>>>(X, fnorm_w, fnorm_b, d_out);
}

// Round 23
// 1411.126 us; speedup vs baseline: 1.0733x; 1.0733x over previous
//
#include <hip/hip_runtime.h>
#include <math.h>

#define NB 8
#define NC 192
#define DIN 384
#define NL 3136
#define ROWS (NB*NL)     // 25088
#define NE 6160
#define NHID 768

typedef unsigned short u16;
typedef unsigned int u32;
typedef unsigned long long u64;
typedef __attribute__((ext_vector_type(8))) short bh8;
typedef __attribute__((ext_vector_type(4))) float f4;

typedef __attribute__((address_space(1))) const void gl_as1;
typedef __attribute__((address_space(3))) void gl_as3;
#define GL16(g, l) __builtin_amdgcn_global_load_lds((gl_as1*)(const void*)(g), (gl_as3*)(void*)(l), 16, 0, 0)

// ---------- helpers ----------
__device__ __forceinline__ float wredsum(float v){
  v += __shfl_xor(v, 1, 64); v += __shfl_xor(v, 2, 64); v += __shfl_xor(v, 4, 64);
  v += __shfl_xor(v, 8, 64); v += __shfl_xor(v, 16, 64); v += __shfl_xor(v, 32, 64);
  return v;
}
__device__ __forceinline__ void edge_decode(int e, int& u, int& v){
  if (e < 3080){ int h = e/55, w = e - h*55; u = h*56 + w; v = u + 1; }
  else { int e2 = e - 3080; int h = e2/56, w = e2 - h*56; u = h*56 + w; v = u + 56; }
}
__device__ __forceinline__ float siluf(float x){ return x / (1.0f + expf(-x)); }
__device__ __forceinline__ float sofplus(float x){ return fmaxf(x, 0.0f) + log1pf(expf(-fabsf(x))); }
__device__ __forceinline__ float geluf(float x){ return 0.5f * x * (1.0f + erff(x * 0.70710678118654752f)); }
__device__ __forceinline__ u16 f2bf(float x){
  u32 u = __float_as_uint(x);
  u32 r = (u + 0x7fffu + ((u >> 16) & 1u)) >> 16;
  return (u16)r;
}
__device__ __forceinline__ float bf2f(u16 h){ return __uint_as_float(((u32)h) << 16); }

// ---------- fused: ln1 || keys || wprep (block ranges) ----------
__global__ __launch_bounds__(256) void keysln_kernel(const float* __restrict__ x,
    const float* __restrict__ g, const float* __restrict__ bt,
    u16* __restrict__ lnout, u64* __restrict__ keys,
    const float* __restrict__ ipw, const float* __restrict__ opw,
    const float* __restrict__ f1w, const float* __restrict__ f2w,
    u16* __restrict__ ipo, u16* __restrict__ opo, u16* __restrict__ f1o, u16* __restrict__ f2o){
  int bid = blockIdx.x;
  int lane = threadIdx.x & 63;
  if (bid < 6272){
    int gw = (int)((bid * 256u + threadIdx.x) >> 6);
    const float* r = x + (size_t)gw * NC;
    float v[3]; float s = 0.f;
#pragma unroll
    for (int j = 0; j < 3; ++j){ v[j] = r[lane + 64*j]; s += v[j]; }
    s = wredsum(s);
    float mu = s * (1.0f / NC);
    float q = 0.f;
#pragma unroll
    for (int j = 0; j < 3; ++j){ float dd = v[j] - mu; q += dd*dd; }
    q = wredsum(q);
    float rs = rsqrtf(q * (1.0f / NC) + 1e-5f);
    u16* o = lnout + (size_t)gw * NC;
#pragma unroll
    for (int j = 0; j < 3; ++j){
      int dch = lane + 64*j;
      o[dch] = f2bf((v[j] - mu) * rs * g[dch] + bt[dch]);
    }
  } else if (bid < 18592){
    int gw = (int)(((bid - 6272) * 256u + threadIdx.x) >> 6);
    if (gw >= NB * NE) return;
    int b = gw / NE, e = gw - b * NE;
    int u, v; edge_decode(e, u, v);
    const float* ru = x + ((size_t)b * NL + u) * NC;
    const float* rv = x + ((size_t)b * NL + v) * NC;
    float s = 0.f, su = 0.f, sv = 0.f;
#pragma unroll
    for (int j = 0; j < 3; ++j){
      float a = ru[lane + 64*j], c = rv[lane + 64*j];
      s += a * c; su += a * a; sv += c * c;
    }
    s = wredsum(s);
    su = wredsum(su);
    sv = wredsum(sv);
    if (lane == 0){
      float nu = sqrtf(su) + 1e-8f;
      float nv = sqrtf(sv) + 1e-8f;
      float cosv = s / (nu * nv);
      float wgt = expf(1.0f - cosv);
      keys[(size_t)b*NE + e] = ((u64)__float_as_uint(wgt) << 32) | (u64)(u32)e;
    }
  } else {
    int wb = bid - 18592;
    const float* W; u16* o; int K; int nk; int base;
    if (wb < 576){ W = ipw; o = ipo; K = 192; nk = 768*192; base = wb; }
    else if (wb < 864){ W = opw; o = opo; K = 384; nk = 192*384; base = wb - 576; }
    else if (wb < 1440){ W = f1w; o = f1o; K = 192; nk = 768*192; base = wb - 864; }
    else { W = f2w; o = f2o; K = 768; nk = 192*768; base = wb - 1440; }
    int i = base*256 + threadIdx.x;
    if (i >= nk) return;
    int r = i / K, c = i - r*K;
    float v = W[i];
    u16 hi = f2bf(v);
    o[(size_t)r * 2 * K + c] = hi;
    o[(size_t)r * 2 * K + K + c] = f2bf(v - bf2f(hi));
  }
}

// ---------- tree body (256 threads): Boruvka + adjl4 + single-wave BFS (r21 best) ----------
__device__ void tree_body(char* sm, int b, const u64* __restrict__ keys_g,
      int* __restrict__ order_g, int* __restrict__ parpos_g, int* __restrict__ pos_g,
      int* __restrict__ lvl_g, int* __restrict__ nlev_g){
  const int t = threadIdx.x;
  const int NT = 256;
  u64* best   = (u64*)sm;            // [3136]
  u16* parent = (u16*)(sm + 25088);
  u16* comp   = (u16*)(sm + 31360);
  u16* mstU   = (u16*)(sm + 37632);
  u16* mstV   = (u16*)(sm + 43904);
  u32* cnts   = (u32*)(sm + 56448);
  u16* adjl4  = (u16*)sm;            // [3136*4] (over best)
  u32* deg    = (u32*)(sm + 25088);  // (over parent+comp)
  u32* fr     = (u32*)(sm + 37632);  // (over mstU+mstV): node | pnode<<16
  u16* ppos   = (u16*)(sm + 50176);

  const u64* kb = keys_g + (size_t)b * NE;
  for (int v = t; v < NL; v += NT) parent[v] = (u16)v;
  if (t == 0){ cnts[0] = 0; cnts[3] = 0xffffffffu; }
  __syncthreads();

  u32 gpass = 0;
  for (int round = 0; round < 24; ++round){
    for (int it = 0; it < 12; ++it){
      bool ch = false;
      for (int c0 = 0; c0 < NL; c0 += NT*4){
        int vv[4]; u16 pv[4]; int nb2 = 0;
#pragma unroll
        for (int j = 0; j < 4; ++j){ int v = c0 + t + j*NT; if (v < NL){ vv[nb2] = v; pv[nb2] = parent[v]; ++nb2; } }
        u16 gp[4];
        for (int j = 0; j < nb2; ++j) gp[j] = parent[pv[j]];
        for (int j = 0; j < nb2; ++j){ if (gp[j] != pv[j]){ parent[vv[j]] = gp[j]; ch = true; } }
      }
      bool docheck = (it & 1);
      if (docheck && ch) cnts[3] = gpass;
      __syncthreads();
      if (docheck){
        u32 seen = cnts[3];
        __syncthreads();
        u32 cur = gpass; ++gpass;
        if (seen != cur) break;
      }
    }
    for (int v = t; v < NL; v += NT){ comp[v] = parent[v]; best[v] = ~0ull; }
    if (t == 0) cnts[2] = 0;
    __syncthreads();
    for (int c0 = 0; c0 < NE; c0 += NT*8){
      int ee[8]; int eu[8], ev[8]; u16 cu[8], cv[8]; u64 kk[8]; int nb2 = 0;
#pragma unroll
      for (int j = 0; j < 8; ++j){
        int e = c0 + t + j*NT;
        if (e < NE){ ee[nb2] = e; int u, v; edge_decode(e, u, v); eu[nb2] = u; ev[nb2] = v; ++nb2; }
      }
      for (int j = 0; j < nb2; ++j){ cu[j] = comp[eu[j]]; cv[j] = comp[ev[j]]; }
      for (int j = 0; j < nb2; ++j){ kk[j] = kb[ee[j]]; }
      for (int j = 0; j < nb2; ++j){
        if (cu[j] != cv[j]){
          atomicMin(&best[cu[j]], kk[j]);
          atomicMin(&best[cv[j]], kk[j]);
        }
      }
    }
    __syncthreads();
    for (int c0 = 0; c0 < NL; c0 += NT*4){
      int rr[4]; u64 bk[4]; int nb2 = 0;
#pragma unroll
      for (int j = 0; j < 4; ++j){ int r = c0 + t + j*NT; if (r < NL){ rr[nb2] = r; ++nb2; } }
      u16 cr[4];
      for (int j = 0; j < nb2; ++j) cr[j] = comp[rr[j]];
      for (int j = 0; j < nb2; ++j) bk[j] = (cr[j] == (u16)rr[j]) ? best[rr[j]] : ~0ull;
      int uu[4], vv2[4]; u16 ru2[4], rv2[4];
      for (int j = 0; j < nb2; ++j){
        if (bk[j] != ~0ull){ int e = (int)(u32)bk[j]; edge_decode(e, uu[j], vv2[j]); }
      }
      for (int j = 0; j < nb2; ++j){
        if (bk[j] != ~0ull){ ru2[j] = comp[uu[j]]; rv2[j] = comp[vv2[j]]; }
      }
      for (int j = 0; j < nb2; ++j){
        if (bk[j] != ~0ull){
          int r = rr[j];
          u16 other = (ru2[j] == (u16)r) ? rv2[j] : ru2[j];
          bool mutual = (best[other] == bk[j]);
          if (!mutual || (u16)r < other){
            parent[r] = other;
            u32 id = atomicAdd(&cnts[0], 1);
            mstU[id] = (u16)uu[j]; mstV[id] = (u16)vv2[j];
            cnts[2] = 1;
          }
        }
      }
    }
    __syncthreads();
    if (cnts[0] >= (u32)(NL - 1) || cnts[2] == 0) break;
  }
  __syncthreads();

  const int nm = NL - 1;
  for (int v = t; v < NL; v += NT){
    deg[v] = 0;
    *(u64*)&adjl4[v*4] = 0xffffffffffffffffull;
  }
  __syncthreads();
  for (int c0 = 0; c0 < nm; c0 += NT*4){
    int uu[4], vv2[4]; int nb2 = 0;
#pragma unroll
    for (int j = 0; j < 4; ++j){
      int i = c0 + t + j*NT;
      if (i < nm){ uu[nb2] = mstU[i]; vv2[nb2] = mstV[i]; ++nb2; }
    }
    for (int j = 0; j < nb2; ++j){
      u32 s1 = atomicAdd(&deg[uu[j]], 1); adjl4[uu[j]*4 + s1] = (u16)vv2[j];
      u32 s2 = atomicAdd(&deg[vv2[j]], 1); adjl4[vv2[j]*4 + s2] = (u16)uu[j];
    }
  }
  __syncthreads();

  if (t == 0){
    fr[0] = 0u | (0xffffu << 16);
    ppos[0] = 0;
    cnts[1] = 1;
    lvl_g[b*3200 + 0] = 0; lvl_g[b*3200 + 1] = 1;
  }
  __syncthreads();
  if (t < 64){
    int flo = 0, fhi = 1, d = 1;
    while (fhi < NL){
      for (int base2 = flo; base2 < fhi; base2 += 64){
        int idx = base2 + t;
        if (idx < fhi){
          u32 f = fr[idx];
          int u = (int)(f & 0xffffu), pn = (int)(f >> 16);
          u64 four = *(const u64*)&adjl4[u*4];
#pragma unroll
          for (int j = 0; j < 4; ++j){
            int v = (int)((four >> (16*j)) & 0xffffu);
            if (v != 0xffff && v != pn){
              u32 pos = atomicAdd(&cnts[1], 1);
              fr[pos] = (u32)v | ((u32)u << 16);
              ppos[pos] = (u16)idx;
            }
          }
        }
        asm volatile("s_waitcnt lgkmcnt(0)" ::: "memory");
      }
      int nf = (int)cnts[1];
      if (t == 0) lvl_g[b*3200 + d + 1] = nf;
      flo = fhi; fhi = nf; ++d;
      if (nf == flo) break;
    }
    if (t == 0) nlev_g[b] = d;
  }
  __syncthreads();

  for (int p = t; p < NL; p += NT){
    u32 f = fr[p];
    int node = (int)(f & 0xffffu);
    order_g[b*NL + p] = node;
    parpos_g[b*NL + p] = (int)ppos[p];
    pos_g[b*NL + node] = p;
  }
}

// ---------- in_proj GEMM body (BN=128, DUALOUT), LDS passed in ----------
__device__ void inproj_body(char* sm, int bid, const u16* __restrict__ Ap, const u16* __restrict__ Wp,
                            float* __restrict__ Cm, float* __restrict__ C2){
  const int K = 192, K2 = 384;
  short* Ah = (short*)sm;              // 128*64
  short* Wh = (short*)(sm + 16384);    // 128*64
  short* Wl = (short*)(sm + 32768);    // 128*64
  const int bn = (bid % 6) * 128, bm = (bid / 6) * 128;
  const int tid = threadIdx.x, lane = tid & 63, wid = tid >> 6;
  const int wr = wid >> 1, wc = wid & 1;
  f4 acc[4][4];
#pragma unroll
  for (int mf = 0; mf < 4; ++mf)
#pragma unroll
    for (int nf = 0; nf < 4; ++nf) acc[mf][nf] = (f4){0.f,0.f,0.f,0.f};

  for (int k0 = 0; k0 < K; k0 += 64){
#pragma unroll
    for (int j = 0; j < 4; ++j){
      int isb = wid*4 + j;
      int r = isb*8 + (lane >> 3);
      int c = lane & 7;
      const u16* src = Ap + (size_t)(bm + r) * K + k0 + ((c ^ (r & 7)) << 3);
      GL16(src, &Ah[isb*512]);
    }
#pragma unroll
    for (int j = 0; j < 4; ++j){
      int isb = wid*4 + j;
      int r = isb*8 + (lane >> 3);
      int c = lane & 7;
      const u16* src = Wp + (size_t)(bn + r) * K2 + k0 + ((c ^ (r & 7)) << 3);
      GL16(src,     &Wh[isb*512]);
      GL16(src + K, &Wl[isb*512]);
    }
    __syncthreads();
#pragma unroll
    for (int kk = 0; kk < 2; ++kk){
      bh8 whf[4], wlf[4], ahf[4];
#pragma unroll
      for (int nf = 0; nf < 4; ++nf){
        int rw = wc*64 + nf*16 + (lane & 15);
        int c = kk*4 + (lane >> 4);
        int ad = rw*64 + ((c ^ (rw & 7)) * 8);
        whf[nf] = *(const bh8*)&Wh[ad];
        wlf[nf] = *(const bh8*)&Wl[ad];
      }
#pragma unroll
      for (int mf = 0; mf < 4; ++mf){
        int ra = wr*64 + mf*16 + (lane & 15);
        int c = kk*4 + (lane >> 4);
        int ad = ra*64 + ((c ^ (ra & 7)) * 8);
        ahf[mf] = *(const bh8*)&Ah[ad];
      }
#pragma unroll
      for (int mf = 0; mf < 4; ++mf)
#pragma unroll
        for (int nf = 0; nf < 4; ++nf){
          acc[mf][nf] = __builtin_amdgcn_mfma_f32_16x16x32_bf16(ahf[mf], whf[nf], acc[mf][nf], 0, 0, 0);
          acc[mf][nf] = __builtin_amdgcn_mfma_f32_16x16x32_bf16(ahf[mf], wlf[nf], acc[mf][nf], 0, 0, 0);
        }
    }
    __syncthreads();
  }
  const int cb = bn + wc*64;
#pragma unroll
  for (int mf = 0; mf < 4; ++mf){
    int row = bm + wr*64 + mf*16 + (lane >> 4)*4;
#pragma unroll
    for (int nf = 0; nf < 4; ++nf){
      int col = cb + nf*16 + (lane & 15);
#pragma unroll
      for (int r = 0; r < 4; ++r){
        float v = acc[mf][nf][r];
        float* op = (col < 384) ? Cm : C2;
        int oc = (col < 384) ? col : col - 384;
        op[(size_t)(row + r) * 384 + oc] = v;
      }
    }
  }
}

// ---------- fused: blocks 0..7 = tree, blocks 8.. = in_proj GEMM ----------
__global__ __launch_bounds__(256) void fused_tree_inproj(
    const u64* __restrict__ keysg, int* __restrict__ ordg, int* __restrict__ ppg,
    int* __restrict__ posg, int* __restrict__ lvlg, int* __restrict__ nlvg,
    const u16* __restrict__ Ap, const u16* __restrict__ Wp,
    float* __restrict__ Cm, float* __restrict__ C2){
  __shared__ __align__(16) char sm[62736];
  int bid = blockIdx.x;
  if (bid < 8){
    tree_body(sm, bid, keysg, ordg, ppg, posg, lvlg, nlvg);
  } else {
    inproj_body(sm, bid - 8, Ap, Wp, Cm, C2);
  }
}

// ---------- fused: blocks 0..7 = window-schedule build, blocks 8.. = conv ----------
__global__ __launch_bounds__(256) void sched_conv_kernel(
    const int* __restrict__ lvl_g, const int* __restrict__ nlev_g,
    u32* __restrict__ wsched_g, int* __restrict__ nwin_g,
    const float* __restrict__ xs, const float* __restrict__ cw,
    const float* __restrict__ cb, float* __restrict__ u){
  __shared__ int lvls[3200];
  int bid = blockIdx.x;
  if (bid < 8){
    int b = bid;
    int tid = threadIdx.x;
    int d = nlev_g[b];
    for (int i = tid; i <= d; i += 256) lvls[i] = lvl_g[b*3200 + i];
    __syncthreads();
    if (tid >= 64) return;
    int lane = tid;
    u32* su = wsched_g + (size_t)b*6528;
    u32* sd = su + 3264;
    int nk = d - 1;
    for (int pass = 0; pass < 2; ++pass){
      u32* out = pass ? sd : su;
      int carry = 0;
      for (int c0 = 0; c0 < nk; c0 += 64){
        int kk = c0 + lane;
        bool valid = kk < nk;
        int lo = 0, hi = 0, wc = 0;
        if (valid){
          int dd = pass ? (1 + kk) : (d - 1 - kk);
          lo = lvls[dd]; hi = lvls[dd+1];
          wc = (hi - lo + 63) >> 6;
        }
        int inc = wc;
        for (int off = 1; off < 64; off <<= 1){
          int v = __shfl_up(inc, off, 64);
          if (lane >= off) inc += v;
        }
        int excl = carry + inc - wc;
        if (valid){
          for (int w = 0; w < wc; ++w){
            int base2 = lo + (w << 6);
            u32 e = (u32)base2 | ((u32)hi << 16);
            if (base2 + 64 >= hi) e |= 0x80000000u;
            out[excl + w] = e;
          }
        }
        carry += __shfl(inc, 63, 64);
      }
      if (lane == 0) nwin_g[b*2 + pass] = carry;
    }
  } else {
    int idx = (bid - 8) * 256 + threadIdx.x;
    if (idx >= ROWS * 96) return;
    int q = idx % 96; int l = idx / 96;
    int b = l / NL; int hw = l - b * NL; int h = hw / 56; int wcc = hw - h * 56;
    int c4 = q * 4;
    float4 acc = *(const float4*)(cb + c4);
#pragma unroll
    for (int kh = 0; kh < 3; ++kh){
      int hh = h + kh - 1; if (hh < 0 || hh >= 56) continue;
#pragma unroll
      for (int kw = 0; kw < 3; ++kw){
        int wwc = wcc + kw - 1; if (wwc < 0 || wwc >= 56) continue;
        float4 iv = *(const float4*)(xs + ((size_t)(b * NL + hh*56 + wwc)) * DIN + c4);
        float4 wv = *(const float4*)(cw + (size_t)(kh*3 + kw) * DIN + c4);
        acc.x += iv.x * wv.x; acc.y += iv.y * wv.y; acc.z += iv.z * wv.z; acc.w += iv.w * wv.w;
      }
    }
    float4 o; o.x = siluf(acc.x); o.y = siluf(acc.y); o.z = siluf(acc.z); o.w = siluf(acc.w);
    *(float4*)(u + (size_t)l * DIN + c4) = o;
  }
}

// ---------- layernorm (wave per row); BF16OUT -> plain bf16 row ----------
template<int D, bool BF16OUT>
__global__ __launch_bounds__(256) void ln_kernel(const float* __restrict__ in, const float* __restrict__ g,
                                                 const float* __restrict__ bt, void* __restrict__ outv){
  int gw = (int)((blockIdx.x * 256u + threadIdx.x) >> 6);
  int lane = threadIdx.x & 63;
  if (gw >= ROWS) return;
  constexpr int J = D / 64;
  const float* r = in + (size_t)gw * D;
  float v[J]; float s = 0.f;
#pragma unroll
  for (int j = 0; j < J; ++j){ v[j] = r[lane + 64*j]; s += v[j]; }
  s = wredsum(s);
  float mu = s * (1.0f / D);
  float q = 0.f;
#pragma unroll
  for (int j = 0; j < J; ++j){ float dd = v[j] - mu; q += dd*dd; }
  q = wredsum(q);
  float rs = rsqrtf(q * (1.0f / D) + 1e-5f);
  if (BF16OUT){
    u16* o = (u16*)outv + (size_t)gw * D;
#pragma unroll
    for (int j = 0; j < J; ++j){
      int dch = lane + 64*j;
      float y = (v[j] - mu) * rs * g[dch] + bt[dch];
      o[dch] = f2bf(y);
    }
  } else {
    float* o = (float*)outv + (size_t)gw * D;
#pragma unroll
    for (int j = 0; j < J; ++j){ int dch = lane + 64*j; o[dch] = (v[j] - mu) * rs * g[dch] + bt[dch]; }
  }
}

// ---------- MFMA GEMM: A plain bf16 [M,K]; W split hi|lo [N,2K]. ----------
template<int BN, bool BIAS, int ACT, bool RESID, bool OBF16, bool DUALOUT>
__global__ __launch_bounds__(256) void mgemm_kernel(
    const u16* __restrict__ Ap, const u16* __restrict__ Wp,
    const float* __restrict__ bias, const float* __restrict__ resid,
    float* __restrict__ Cm, float* __restrict__ C2, int M, int N, int K){
  static_assert(BN == 64 || BN == 128, "BN");
  constexpr int WT = (BN == 128) ? 64 : 32;
  constexpr int NF = WT / 16;
  __shared__ short Ah[128*64];
  __shared__ short Wh[BN*64], Wl[BN*64];
  const int bm = blockIdx.y * 128, bn = blockIdx.x * BN;
  const int tid = threadIdx.x, lane = tid & 63, wid = tid >> 6;
  const int wr = wid >> 1, wc = wid & 1;
  const int K2 = 2 * K;
  f4 acc[4][NF];
#pragma unroll
  for (int mf = 0; mf < 4; ++mf)
#pragma unroll
    for (int nf = 0; nf < NF; ++nf) acc[mf][nf] = (f4){0.f,0.f,0.f,0.f};

  for (int k0 = 0; k0 < K; k0 += 64){
#pragma unroll
    for (int j = 0; j < 4; ++j){
      int isb = wid*4 + j;
      int r = isb*8 + (lane >> 3);
      int c = lane & 7;
      const u16* src = Ap + (size_t)(bm + r) * K + k0 + ((c ^ (r & 7)) << 3);
      GL16(src, &Ah[isb*512]);
    }
#pragma unroll
    for (int j = 0; j < BN/32; ++j){
      int isb = wid*(BN/32) + j;
      int r = isb*8 + (lane >> 3);
      int c = lane & 7;
      const u16* src = Wp + (size_t)(bn + r) * K2 + k0 + ((c ^ (r & 7)) << 3);
      GL16(src,     &Wh[isb*512]);
      GL16(src + K, &Wl[isb*512]);
    }
    __syncthreads();
#pragma unroll
    for (int kk = 0; kk < 2; ++kk){
      bh8 whf[NF], wlf[NF], ahf[4];
#pragma unroll
      for (int nf = 0; nf < NF; ++nf){
        int rw = wc*WT + nf*16 + (lane & 15);
        int c = kk*4 + (lane >> 4);
        int ad = rw*64 + ((c ^ (rw & 7)) * 8);
        whf[nf] = *(const bh8*)&Wh[ad];
        wlf[nf] = *(const bh8*)&Wl[ad];
      }
#pragma unroll
      for (int mf = 0; mf < 4; ++mf){
        int ra = wr*64 + mf*16 + (lane & 15);
        int c = kk*4 + (lane >> 4);
        int ad = ra*64 + ((c ^ (ra & 7)) * 8);
        ahf[mf] = *(const bh8*)&Ah[ad];
      }
#pragma unroll
      for (int mf = 0; mf < 4; ++mf)
#pragma unroll
        for (int nf = 0; nf < NF; ++nf){
          acc[mf][nf] = __builtin_amdgcn_mfma_f32_16x16x32_bf16(ahf[mf], whf[nf], acc[mf][nf], 0, 0, 0);
          acc[mf][nf] = __builtin_amdgcn_mfma_f32_16x16x32_bf16(ahf[mf], wlf[nf], acc[mf][nf], 0, 0, 0);
        }
    }
    __syncthreads();
  }
  const int cb = bn + wc*WT;
#pragma unroll
  for (int mf = 0; mf < 4; ++mf){
    int row = bm + wr*64 + mf*16 + (lane >> 4)*4;
#pragma unroll
    for (int nf = 0; nf < NF; ++nf){
      int col = cb + nf*16 + (lane & 15);
#pragma unroll
      for (int r = 0; r < 4; ++r){
        float v = acc[mf][nf][r];
        if (BIAS) v += bias[col];
        if (ACT == 1) v = geluf(v);
        if (RESID) v += resid[(size_t)(row + r) * N + col];
        if (DUALOUT){
          float* op = (col < 384) ? Cm : C2;
          int oc = (col < 384) ? col : col - 384;
          op[(size_t)(row + r) * 384 + oc] = v;
        } else if (OBF16){
          u16* op = (u16*)Cm;
          op[(size_t)(row + r) * N + col] = f2bf(v);
        } else {
          Cm[(size_t)(row + r) * N + col] = v;
        }
      }
    }
  }
}

// ---------- x_proj + dt_proj + softplus + w/feat (wave per row), BFS-pos output ----------
__global__ __launch_bounds__(256) void xdbl_kernel(const float* __restrict__ u,
    const float* __restrict__ xpw, const float* __restrict__ dtw_g,
    const float* __restrict__ dtb, const float* __restrict__ alog, const int* __restrict__ pos_g,
    float* __restrict__ wout, float* __restrict__ fout, float* __restrict__ csout){
  __shared__ float xw[14*384];
  __shared__ float dw[384*12];
  __shared__ float db[384];
  __shared__ float An[384];
  int t = threadIdx.x;
  for (int i = t; i < 14*384; i += 256) xw[i] = xpw[i];
  for (int i = t; i < 384*12; i += 256) dw[i] = dtw_g[i];
  for (int i = t; i < 384; i += 256){ db[i] = dtb[i]; An[i] = -expf(alog[i]); }
  __syncthreads();
  int wave = t >> 6, lane = t & 63;
  int row0 = blockIdx.x * 16 + wave * 4;
  for (int rr = 0; rr < 4; ++rr){
    int m = row0 + rr;
    int b = m / NL;
    int pos = pos_g[m];
    size_t orow = ((size_t)b * NL + pos) * DIN;
    const float* ur = u + (size_t)m * DIN;
    float u6[6];
#pragma unroll
    for (int j = 0; j < 6; ++j) u6[j] = ur[lane + 64*j];
    float xd[14];
#pragma unroll
    for (int r = 0; r < 14; ++r){
      float p = 0.f;
#pragma unroll
      for (int j = 0; j < 6; ++j) p += u6[j] * xw[r*384 + lane + 64*j];
      xd[r] = wredsum(p);
    }
    float Bs = xd[12], Cv = xd[13];
#pragma unroll
    for (int j = 0; j < 6; ++j){
      int dch = lane + 64*j;
      float pre = db[dch];
#pragma unroll
      for (int r = 0; r < 12; ++r) pre += xd[r] * dw[dch*12 + r];
      float dts = sofplus(pre);
      float wv = expf(dts * An[dch]);
      float fv = dts * Bs * u6[j];
      wout[orow + dch] = wv;
      fout[orow + dch] = fv;
    }
    if (lane == 0) csout[m] = Cv;
  }
}

// ---------- w transpose: [b][pos][384] -> planar [b][ch][pos] (64x64 LDS tiles) ----------
__global__ __launch_bounds__(256) void wtr_kernel(const float* __restrict__ in, float* __restrict__ out){
  __shared__ float tile[64][65];
  int blk = blockIdx.x;
  int b = blk / (49*6);
  int r = blk - b*(49*6);
  int pt = r / 6, ct = r - pt*6;
  int t = threadIdx.x;
  int tr = t >> 6, lane = t & 63;
  const float* src = in + ((size_t)b*NL + (size_t)pt*64) * DIN + ct*64;
#pragma unroll
  for (int k = 0; k < 16; ++k){
    int rr = tr + k*4;
    tile[rr][lane] = src[(size_t)rr*DIN + lane];
  }
  __syncthreads();
  float* dst = out + ((size_t)b*DIN + (size_t)ct*64) * NL + (size_t)pt*64;
#pragma unroll
  for (int k = 0; k < 16; ++k){
    int cc = tr + k*4;
    dst[(size_t)cc*NL + lane] = tile[lane][cc];
  }
}

// ---------- sweep8: flat window schedule + depth-2 w/pp prefetch. ----------
template<bool UP>
__device__ __forceinline__ void sweep_run(const u32* __restrict__ sc, int nw,
    float* __restrict__ Sp, const float* __restrict__ wbase, const int* __restrict__ pg, int lane){
  if (nw <= 0) return;
  u32 d0 = sc[lane];
  u32 d1 = sc[64 + lane];
  int curch = 0;
  float wA = 0.f, wB = 0.f; int pA = 0, pB = 0;
  int baseA = 0, hiA = 0, baseB = 0, hiB = 0;
  u32 eA = 0, eB = 0; bool aA = false, aB = false;
  {
    u32 dc = __shfl(d0, 0, 64);
    baseA = (int)(dc & 0xffffu); hiA = (int)((dc >> 16) & 0x7fffu); eA = dc >> 31;
    int p = baseA + lane; aA = p < hiA;
    if (aA){ wA = wbase[p]; pA = pg[p]; }
  }
  if (nw > 1){
    u32 dc = __shfl(d0, 1, 64);
    baseB = (int)(dc & 0xffffu); hiB = (int)((dc >> 16) & 0x7fffu); eB = dc >> 31;
    int p = baseB + lane; aB = p < hiB;
    if (aB){ wB = wbase[p]; pB = pg[p]; }
  }
  for (int iw = 0; iw < nw; ++iw){
    int ch = iw >> 6;
    if (ch != curch){ d0 = d1; d1 = sc[(ch + 1)*64 + lane]; curch = ch; }
    float wN = 0.f; int pN = 0; int baseN = 0, hiN = 0; u32 eN = 0; bool aN = false;
    int iw2 = iw + 2;
    if (iw2 < nw){
      int ch2 = iw2 >> 6;
      u32 dc2 = __shfl((ch2 == curch) ? d0 : d1, iw2 & 63, 64);
      baseN = (int)(dc2 & 0xffffu); hiN = (int)((dc2 >> 16) & 0x7fffu); eN = dc2 >> 31;
      int p = baseN + lane; aN = p < hiN;
      if (aN){ wN = wbase[p]; pN = pg[p]; }
    }
    int p = baseA + lane;
    if (aA){
      if (UP){
        float s = Sp[p];
        atomicAdd(&Sp[pA], wA * s);
      } else {
        float s = Sp[p]; float h = Sp[pA];
        Sp[p] = s + wA * (h - wA * s);
      }
    }
    if (eA){
      asm volatile("s_waitcnt lgkmcnt(0)" ::: "memory");
    }
    baseA = baseB; hiA = hiB; aA = aB; wA = wB; pA = pB; eA = eB;
    baseB = baseN; hiB = hiN; aB = aN; wB = wN; pB = pN; eB = eN;
  }
}

__global__ __launch_bounds__(256) void sweep8_kernel(const float* __restrict__ featp, const float* __restrict__ wtr,
    float* __restrict__ Hp, const int* __restrict__ parpos_g,
    const u32* __restrict__ wsched_g, const int* __restrict__ nwin_g){
  __shared__ float S[4*NL];    // 50176B -> 3 blocks/CU
  int blk = blockIdx.x;
  int b = blk & 7, q = blk >> 3;   // tree b pinned to XCD b
  int t = threadIdx.x, lane = t & 63, wv = t >> 6;
  const int* pg = parpos_g + b*NL;
  const float* fbase = featp + (size_t)b*NL*DIN + q*4;
  const float* wbase = wtr + ((size_t)b*DIN + q*4 + wv) * NL;
  float*       hbase = Hp    + (size_t)b*NL*DIN + q*4;
  for (int i = t; i < NL; i += 256){
    float4 f = *(const float4*)(fbase + (size_t)i*DIN);
    S[0*NL + i] = f.x; S[1*NL + i] = f.y; S[2*NL + i] = f.z; S[3*NL + i] = f.w;
  }
  __syncthreads();
  float* Sp = &S[wv*NL];

  const u32* su = wsched_g + (size_t)b*6528;
  const u32* sd = su + 3264;
  int nwu = nwin_g[b*2], nwd = nwin_g[b*2 + 1];
  sweep_run<true>(su, nwu, Sp, wbase, pg, lane);
  sweep_run<false>(sd, nwd, Sp, wbase, pg, lane);

  __syncthreads();
  for (int i = t; i < NL; i += 256){
    float4 o;
    o.x = S[0*NL + i]; o.y = S[1*NL + i]; o.z = S[2*NL + i]; o.w = S[3*NL + i];
    *(float4*)(hbase + (size_t)i*DIN) = o;
  }
}

// ---------- y = Cs*H + Ds*u -> LN -> * silu(z) -> plain bf16 (pos-row input) ----------
__global__ __launch_bounds__(256) void ynorm_kernel(const float* __restrict__ Hp, const float* __restrict__ u,
    const float* __restrict__ z, const float* __restrict__ Cs, const int* __restrict__ order_g,
    const float* __restrict__ Ds, const float* __restrict__ g, const float* __restrict__ bt,
    u16* __restrict__ out){
  int gw = (int)((blockIdx.x * 256u + threadIdx.x) >> 6);   // pos-row
  int lane = threadIdx.x & 63;
  if (gw >= ROWS) return;
  int b = gw / NL;
  int node = order_g[gw];
  size_t nrow = (size_t)b * NL + node;
  float Cv = Cs[nrow];
  const float* hr = Hp + (size_t)gw * DIN;
  const float* ur = u + nrow * DIN;
  const float* zr = z + nrow * DIN;
  float y[6]; float s = 0.f;
#pragma unroll
  for (int j = 0; j < 6; ++j){
    int dch = lane + 64*j;
    y[j] = Cv * hr[dch] + Ds[dch] * ur[dch];
    s += y[j];
  }
  s = wredsum(s);
  float mu = s * (1.0f / DIN);
  float q = 0.f;
#pragma unroll
  for (int j = 0; j < 6; ++j){ float dd = y[j] - mu; q += dd*dd; }
  q = wredsum(q);
  float rs = rsqrtf(q * (1.0f / DIN) + 1e-5f);
  u16* o = out + nrow * DIN;
#pragma unroll
  for (int j = 0; j < 6; ++j){
    int dch = lane + 64*j;
    float yn = (y[j] - mu) * rs * g[dch] + bt[dch];
    float v = yn * siluf(zr[dch]);
    o[dch] = f2bf(v);
  }
}

// ---------- host orchestration ----------
extern "C" void kernel_launch(void* const* d_in, const int* in_sizes, int n_in,
                              void* d_out, int out_size, void* d_ws, size_t ws_size,
                              hipStream_t stream){
  const float* x_in       = (const float*)d_in[0];
  const float* norm1_w    = (const float*)d_in[1];
  const float* norm1_b    = (const float*)d_in[2];
  const float* in_proj_w  = (const float*)d_in[3];
  const float* conv_w     = (const float*)d_in[4];
  const float* conv_b     = (const float*)d_in[5];
  const float* x_proj_w   = (const float*)d_in[6];
  const float* dt_proj_w  = (const float*)d_in[7];
  const float* dt_proj_b  = (const float*)d_in[8];
  const float* A_log      = (const float*)d_in[9];
  const float* Ds         = (const float*)d_in[10];
  const float* out_norm_w = (const float*)d_in[11];
  const float* out_norm_b = (const float*)d_in[12];
  const float* out_proj_w = (const float*)d_in[13];
  const float* norm2_w    = (const float*)d_in[14];
  const float* norm2_b    = (const float*)d_in[15];
  const float* fc1_w      = (const float*)d_in[16];
  const float* fc1_b      = (const float*)d_in[17];
  const float* fc2_w      = (const float*)d_in[18];
  const float* fc2_b      = (const float*)d_in[19];
  const float* fnorm_w    = (const float*)d_in[20];
  const float* fnorm_b    = (const float*)d_in[21];

  float* ws = (float*)d_ws;
  float* X     = ws + 0;
  u16*   bufAh = (u16*)(ws + 4816896);
  float* bufZ  = ws + 9633792;
  float* bufW  = ws + 19267584;
  float* bufU  = ws + 28901376;
  float* bufF  = ws + 38535168;
  u16*   Gp    = (u16*)bufU;
  float* Csb   = ws + 48168960;
  int*   ordg  = (int*)(ws + 48194048);
  int*   ppg   = (int*)(ws + 48219136);
  int*   lvlg  = (int*)(ws + 48244224);
  int*   nlvg  = (int*)(ws + 48269824);
  u64*   keysg = (u64*)(ws + 48269832);
  u16*   ipWp  = (u16*)(ws + 48393480);
  u16*   opWp  = (u16*)(ws + 48540936);
  u16*   fc1Wp = (u16*)(ws + 48614664);
  u16*   fc2Wp = (u16*)(ws + 48762120);
  int*   posg  = (int*)(ws + 48909576);
  float* wtrp  = ws + 48934664;          // planar w [b][384][NL]
  u32*   wschg = (u32*)(ws + 58568456);  // 8*6528 u32
  int*   nwing = (int*)(ws + 58620680);  // 16 ints

  hipMemcpyAsync(X, x_in, (size_t)ROWS * NC * sizeof(float), hipMemcpyDeviceToDevice, stream);

  for (int i = 0; i < 2; ++i){
    // ln1 (0..6271) || keys (6272..18591) || wprep (18592..20607)
    keysln_kernel<<<20608, 256, 0, stream>>>(X, norm1_w + i*NC, norm1_b + i*NC, bufAh, keysg,
                                             in_proj_w + (size_t)i*NHID*NC, out_proj_w + (size_t)i*NC*DIN,
                                             fc1_w + (size_t)i*NHID*NC, fc2_w + (size_t)i*NC*NHID,
                                             ipWp, opWp, fc1Wp, fc2Wp);

    // fused: tree (blocks 0..7) + in_proj GEMM (blocks 8..1183)
    fused_tree_inproj<<<8 + 6*196, 256, 0, stream>>>(keysg, ordg, ppg, posg, lvlg, nlvg,
                                                     bufAh, ipWp, bufF, bufZ);

    // sched (blocks 0..7) || conv (blocks 8..9415)
    sched_conv_kernel<<<8 + (ROWS*96)/256, 256, 0, stream>>>(lvlg, nlvg, wschg, nwing,
                                                             bufF, conv_w + (size_t)i*9*DIN, conv_b + i*DIN, bufU);

    xdbl_kernel<<<ROWS/16, 256, 0, stream>>>(bufU, x_proj_w + (size_t)i*14*DIN, dt_proj_w + (size_t)i*DIN*12,
                                             dt_proj_b + i*DIN, A_log + i*DIN, posg, bufW, bufF, Csb);

    wtr_kernel<<<8*49*6, 256, 0, stream>>>(bufW, wtrp);

    sweep8_kernel<<<NB*96, 256, 0, stream>>>(bufF, wtrp, bufF, ppg, wschg, nwing);

    ynorm_kernel<<<ROWS/4, 256, 0, stream>>>(bufF, bufU, bufZ, Csb, ordg, Ds + i*DIN,
                                             out_norm_w + i*DIN, out_norm_b + i*DIN, (u16*)bufW);

    mgemm_kernel<64,false,0,true,false,false><<<dim3(3,196), 256, 0, stream>>>((u16*)bufW, opWp, nullptr, X, X, nullptr, ROWS, 192, 384);

    ln_kernel<192,true><<<ROWS/4, 256, 0, stream>>>(X, norm2_w + i*NC, norm2_b + i*NC, bufAh);
    mgemm_kernel<128,true,1,false,true,false><<<dim3(6,196), 256, 0, stream>>>(bufAh, fc1Wp, fc1_b + i*NHID, nullptr, (float*)Gp, nullptr, ROWS, NHID, 192);
    mgemm_kernel<64,true,0,true,false,false><<<dim3(3,196), 256, 0, stream>>>(Gp, fc2Wp, fc2_b + i*NC, X, X, nullptr, ROWS, 192, 768);
  }

  ln_kernel<192,false><<<ROWS/4, 256, 0, stream>>>(X, fnorm_w, fnorm_b, d_out);
}

// Round 24
// 1291.566 us; speedup vs baseline: 1.1726x; 1.0926x over previous
//
#include <hip/hip_runtime.h>
#include <math.h>

#define NB 8
#define NC 192
#define DIN 384
#define NL 3136
#define ROWS (NB*NL)     // 25088
#define NE 6160
#define NHID 768

typedef unsigned short u16;
typedef unsigned int u32;
typedef unsigned long long u64;
typedef __attribute__((ext_vector_type(8))) short bh8;
typedef __attribute__((ext_vector_type(4))) float f4;

typedef __attribute__((address_space(1))) const void gl_as1;
typedef __attribute__((address_space(3))) void gl_as3;
#define GL16(g, l) __builtin_amdgcn_global_load_lds((gl_as1*)(const void*)(g), (gl_as3*)(void*)(l), 16, 0, 0)

// ---------- helpers ----------
__device__ __forceinline__ float wredsum(float v){
  v += __shfl_xor(v, 1, 64); v += __shfl_xor(v, 2, 64); v += __shfl_xor(v, 4, 64);
  v += __shfl_xor(v, 8, 64); v += __shfl_xor(v, 16, 64); v += __shfl_xor(v, 32, 64);
  return v;
}
__device__ __forceinline__ void edge_decode(int e, int& u, int& v){
  if (e < 3080){ int h = e/55, w = e - h*55; u = h*56 + w; v = u + 1; }
  else { int e2 = e - 3080; int h = e2/56, w = e2 - h*56; u = h*56 + w; v = u + 56; }
}
__device__ __forceinline__ float siluf(float x){ return x / (1.0f + expf(-x)); }
__device__ __forceinline__ float sofplus(float x){ return fmaxf(x, 0.0f) + log1pf(expf(-fabsf(x))); }
__device__ __forceinline__ float geluf(float x){ return 0.5f * x * (1.0f + erff(x * 0.70710678118654752f)); }
__device__ __forceinline__ u16 f2bf(float x){
  u32 u = __float_as_uint(x);
  u32 r = (u + 0x7fffu + ((u >> 16) & 1u)) >> 16;
  return (u16)r;
}
__device__ __forceinline__ float bf2f(u16 h){ return __uint_as_float(((u32)h) << 16); }

// ---------- fused: ln1 || keys || wprep (block ranges) ----------
__global__ __launch_bounds__(256) void keysln_kernel(const float* __restrict__ x,
    const float* __restrict__ g, const float* __restrict__ bt,
    u16* __restrict__ lnout, u64* __restrict__ keys,
    const float* __restrict__ ipw, const float* __restrict__ opw,
    const float* __restrict__ f1w, const float* __restrict__ f2w,
    u16* __restrict__ ipo, u16* __restrict__ opo, u16* __restrict__ f1o, u16* __restrict__ f2o){
  int bid = blockIdx.x;
  int lane = threadIdx.x & 63;
  if (bid < 6272){
    int gw = (int)((bid * 256u + threadIdx.x) >> 6);
    const float* r = x + (size_t)gw * NC;
    float v[3]; float s = 0.f;
#pragma unroll
    for (int j = 0; j < 3; ++j){ v[j] = r[lane + 64*j]; s += v[j]; }
    s = wredsum(s);
    float mu = s * (1.0f / NC);
    float q = 0.f;
#pragma unroll
    for (int j = 0; j < 3; ++j){ float dd = v[j] - mu; q += dd*dd; }
    q = wredsum(q);
    float rs = rsqrtf(q * (1.0f / NC) + 1e-5f);
    u16* o = lnout + (size_t)gw * NC;
#pragma unroll
    for (int j = 0; j < 3; ++j){
      int dch = lane + 64*j;
      o[dch] = f2bf((v[j] - mu) * rs * g[dch] + bt[dch]);
    }
  } else if (bid < 18592){
    int gw = (int)(((bid - 6272) * 256u + threadIdx.x) >> 6);
    if (gw >= NB * NE) return;
    int b = gw / NE, e = gw - b * NE;
    int u, v; edge_decode(e, u, v);
    const float* ru = x + ((size_t)b * NL + u) * NC;
    const float* rv = x + ((size_t)b * NL + v) * NC;
    float s = 0.f, su = 0.f, sv = 0.f;
#pragma unroll
    for (int j = 0; j < 3; ++j){
      float a = ru[lane + 64*j], c = rv[lane + 64*j];
      s += a * c; su += a * a; sv += c * c;
    }
    s = wredsum(s);
    su = wredsum(su);
    sv = wredsum(sv);
    if (lane == 0){
      float nu = sqrtf(su) + 1e-8f;
      float nv = sqrtf(sv) + 1e-8f;
      float cosv = s / (nu * nv);
      float wgt = expf(1.0f - cosv);
      keys[(size_t)b*NE + e] = ((u64)__float_as_uint(wgt) << 32) | (u64)(u32)e;
    }
  } else {
    int wb = bid - 18592;
    const float* W; u16* o; int K; int nk; int base;
    if (wb < 576){ W = ipw; o = ipo; K = 192; nk = 768*192; base = wb; }
    else if (wb < 864){ W = opw; o = opo; K = 384; nk = 192*384; base = wb - 576; }
    else if (wb < 1440){ W = f1w; o = f1o; K = 192; nk = 768*192; base = wb - 864; }
    else { W = f2w; o = f2o; K = 768; nk = 192*768; base = wb - 1440; }
    int i = base*256 + threadIdx.x;
    if (i >= nk) return;
    int r = i / K, c = i - r*K;
    float v = W[i];
    u16 hi = f2bf(v);
    o[(size_t)r * 2 * K + c] = hi;
    o[(size_t)r * 2 * K + K + c] = f2bf(v - bf2f(hi));
  }
}

// ---------- tree body (256 threads): Boruvka + adjl4 + Euler-tour parallel ordering ----------
__device__ void tree_body(char* sm, int b, const u64* __restrict__ keys_g,
      int* __restrict__ order_g, int* __restrict__ parpos_g, int* __restrict__ pos_g,
      int* __restrict__ lvl_g, int* __restrict__ nlev_g){
  const int t = threadIdx.x;
  const int NT = 256;
  u64* best   = (u64*)sm;            // [3136]
  u16* parent = (u16*)(sm + 25088);
  u16* comp   = (u16*)(sm + 31360);
  u16* mstU   = (u16*)(sm + 37632);
  u16* mstV   = (u16*)(sm + 43904);
  u32* cnts   = (u32*)(sm + 56448);
  u16* adjl4  = (u16*)sm;            // [3136*4] (over best)
  u32* deg    = (u32*)(sm + 25088);  // (over parent+comp)

  const u64* kb = keys_g + (size_t)b * NE;
  for (int v = t; v < NL; v += NT) parent[v] = (u16)v;
  if (t == 0){ cnts[0] = 0; cnts[3] = 0xffffffffu; }
  __syncthreads();

  u32 gpass = 0;
  for (int round = 0; round < 24; ++round){
    for (int it = 0; it < 12; ++it){
      bool ch = false;
      for (int c0 = 0; c0 < NL; c0 += NT*4){
        int vv[4]; u16 pv[4]; int nb2 = 0;
#pragma unroll
        for (int j = 0; j < 4; ++j){ int v = c0 + t + j*NT; if (v < NL){ vv[nb2] = v; pv[nb2] = parent[v]; ++nb2; } }
        u16 gp[4];
        for (int j = 0; j < nb2; ++j) gp[j] = parent[pv[j]];
        for (int j = 0; j < nb2; ++j){ if (gp[j] != pv[j]){ parent[vv[j]] = gp[j]; ch = true; } }
      }
      bool docheck = (it & 1);
      if (docheck && ch) cnts[3] = gpass;
      __syncthreads();
      if (docheck){
        u32 seen = cnts[3];
        __syncthreads();
        u32 cur = gpass; ++gpass;
        if (seen != cur) break;
      }
    }
    for (int v = t; v < NL; v += NT){ comp[v] = parent[v]; best[v] = ~0ull; }
    if (t == 0) cnts[2] = 0;
    __syncthreads();
    for (int c0 = 0; c0 < NE; c0 += NT*8){
      int ee[8]; int eu[8], ev[8]; u16 cu[8], cv[8]; u64 kk[8]; int nb2 = 0;
#pragma unroll
      for (int j = 0; j < 8; ++j){
        int e = c0 + t + j*NT;
        if (e < NE){ ee[nb2] = e; int u, v; edge_decode(e, u, v); eu[nb2] = u; ev[nb2] = v; ++nb2; }
      }
      for (int j = 0; j < nb2; ++j){ cu[j] = comp[eu[j]]; cv[j] = comp[ev[j]]; }
      for (int j = 0; j < nb2; ++j){ kk[j] = kb[ee[j]]; }
      for (int j = 0; j < nb2; ++j){
        if (cu[j] != cv[j]){
          atomicMin(&best[cu[j]], kk[j]);
          atomicMin(&best[cv[j]], kk[j]);
        }
      }
    }
    __syncthreads();
    for (int c0 = 0; c0 < NL; c0 += NT*4){
      int rr[4]; u64 bk[4]; int nb2 = 0;
#pragma unroll
      for (int j = 0; j < 4; ++j){ int r = c0 + t + j*NT; if (r < NL){ rr[nb2] = r; ++nb2; } }
      u16 cr[4];
      for (int j = 0; j < nb2; ++j) cr[j] = comp[rr[j]];
      for (int j = 0; j < nb2; ++j) bk[j] = (cr[j] == (u16)rr[j]) ? best[rr[j]] : ~0ull;
      int uu[4], vv2[4]; u16 ru2[4], rv2[4];
      for (int j = 0; j < nb2; ++j){
        if (bk[j] != ~0ull){ int e = (int)(u32)bk[j]; edge_decode(e, uu[j], vv2[j]); }
      }
      for (int j = 0; j < nb2; ++j){
        if (bk[j] != ~0ull){ ru2[j] = comp[uu[j]]; rv2[j] = comp[vv2[j]]; }
      }
      for (int j = 0; j < nb2; ++j){
        if (bk[j] != ~0ull){
          int r = rr[j];
          u16 other = (ru2[j] == (u16)r) ? rv2[j] : ru2[j];
          bool mutual = (best[other] == bk[j]);
          if (!mutual || (u16)r < other){
            parent[r] = other;
            u32 id = atomicAdd(&cnts[0], 1);
            mstU[id] = (u16)uu[j]; mstV[id] = (u16)vv2[j];
            cnts[2] = 1;
          }
        }
      }
    }
    __syncthreads();
    if (cnts[0] >= (u32)(NL - 1) || cnts[2] == 0) break;
  }
  __syncthreads();

  const int nm = NL - 1;
  for (int v = t; v < NL; v += NT){
    deg[v] = 0;
    *(u64*)&adjl4[v*4] = 0xffffffffffffffffull;
  }
  __syncthreads();
  for (int c0 = 0; c0 < nm; c0 += NT*4){
    int uu[4], vv2[4]; int nb2 = 0;
#pragma unroll
    for (int j = 0; j < 4; ++j){
      int i = c0 + t + j*NT;
      if (i < nm){ uu[nb2] = mstU[i]; vv2[nb2] = mstV[i]; ++nb2; }
    }
    for (int j = 0; j < nb2; ++j){
      u32 s1 = atomicAdd(&deg[uu[j]], 1); adjl4[uu[j]*4 + s1] = (u16)vv2[j];
      u32 s2 = atomicAdd(&deg[vv2[j]], 1); adjl4[vv2[j]*4 + s2] = (u16)uu[j];
    }
  }
  __syncthreads();

  // ===== Euler-tour parallel ordering (replaces single-wave BFS) =====
  // LDS overlay plan (phase-ordered, all regions within sm[62736]):
  //   adjl4 @0      [25088]  live through phase C2
  //   deg   @25088  [12544]  dead after arcB built; rankA u16[6270] overlays; then hist u32[3136]
  //   arcB  @37632  [6274]   live through C2; then posA u16[3136]
  //   nxt   @43908  [12540]  dead after doubling; then S16 i16[6270]; then parA u16[3136]
  //   dep   @56448  [6272]   u16[3136], from C1 to end
  //   wsum  @62720  [16]     4 wave-partials for scans
  const int NARC = 2 * (NL - 1);   // 6270
  u16*  arcB  = (u16*)(sm + 37632);
  u16*  nxt   = (u16*)(sm + 43908);
  u16*  rankA = (u16*)(sm + 25088);
  short* S16  = (short*)(sm + 43908);
  u16*  parA  = (u16*)(sm + 43908);
  u32*  hist  = (u32*)(sm + 25088);
  u16*  posA  = (u16*)(sm + 37632);
  u16*  dep   = (u16*)(sm + 56448);
  u32*  wsum  = (u32*)(sm + 62720);
  const int lane = t & 63, wv = t >> 6;

  // --- X-a: arcB = exclusive prefix of deg (CH=13 two-level scan) ---
  {
    int dloc[13]; int st = 0;
#pragma unroll
    for (int j = 0; j < 13; ++j){
      int v = t*13 + j;
      dloc[j] = (v < NL) ? (int)deg[v] : 0;
      st += dloc[j];
    }
    int inc = st;
#pragma unroll
    for (int off = 1; off < 64; off <<= 1){
      int sh = __shfl_up(inc, off, 64);
      if (lane >= off) inc += sh;
    }
    if (lane == 63) wsum[wv] = (u32)inc;
    __syncthreads();
    int woff = 0;
    for (int k = 0; k < 4; ++k) if (k < wv) woff += (int)wsum[k];
    int run = woff + inc - st;
#pragma unroll
    for (int j = 0; j < 13; ++j){
      int v = t*13 + j;
      if (v < NL) arcB[v] = (u16)run;
      run += dloc[j];
    }
    if (t == 255) arcB[NL] = (u16)run;   // == NARC
  }
  __syncthreads();

  // --- X-b: Euler successors. arc (u,slot) -> compact id arcB[u]+slot ---
  for (int idx = t; idx < NL*4; idx += NT){
    int u = idx >> 2, sl = idx & 3;
    int v = (int)adjl4[idx];
    if (v != 0xffff){
      int dv = (int)(arcB[v+1] - arcB[v]);
      int rs = 0;
#pragma unroll
      for (int j = 0; j < 4; ++j) if ((int)adjl4[v*4+j] == u) rs = j;
      int ns = rs + 1; if (ns >= dv) ns = 0;
      nxt[arcB[u] + sl] = (u16)(arcB[v] + ns);
    }
  }
  __syncthreads();
  // --- X-c: break cycle at a0 = arc 0 (root node 0, slot 0; arcB[0]==0) ---
  for (int a = t; a < NARC; a += NT){
    if (nxt[a] == 0) nxt[a] = 0xffff;
  }
  __syncthreads();

  // --- Y: list ranking by pointer doubling (rank = distance to tour end) ---
  for (int a = t; a < NARC; a += NT) rankA[a] = (nxt[a] == 0xffff) ? (u16)0 : (u16)1;
  __syncthreads();
  for (int it = 0; it < 13; ++it){
    u16 nn[25], rr2[25];
#pragma unroll
    for (int k = 0; k < 25; ++k){
      int a = t + k*NT;
      nn[k] = 0xfffe; rr2[k] = 0;
      if (a < NARC){
        u16 n = nxt[a];
        if (n != 0xffff){ rr2[k] = rankA[n]; nn[k] = nxt[n]; }
      }
    }
    __syncthreads();
#pragma unroll
    for (int k = 0; k < 25; ++k){
      int a = t + k*NT;
      if (a < NARC && nn[k] != 0xfffe){
        rankA[a] = (u16)(rankA[a] + rr2[k]);
        nxt[a] = nn[k];
      }
    }
    __syncthreads();
  }

  // --- A: write tour deltas (+1 down / -1 up) at tour positions (over nxt) ---
  for (int idx = t; idx < NL*4; idx += NT){
    int u = idx >> 2, sl = idx & 3;
    int v = (int)adjl4[idx];
    if (v != 0xffff){
      int a  = arcB[u] + sl;
      int rs = 0;
#pragma unroll
      for (int j = 0; j < 4; ++j) if ((int)adjl4[v*4+j] == u) rs = j;
      int ar = arcB[v] + rs;
      bool down = rankA[a] > rankA[ar];
      int pt = (NARC - 1) - (int)rankA[a];
      S16[pt] = down ? (short)1 : (short)-1;
    }
  }
  __syncthreads();

  // --- B: inclusive scan of S16 (CH=25 contiguous per thread) ---
  {
    int base = t * 25;
    int vals[25]; int st = 0;
#pragma unroll
    for (int j = 0; j < 25; ++j){
      int i = base + j;
      vals[j] = (i < NARC) ? (int)S16[i] : 0;
      st += vals[j];
    }
    int inc = st;
#pragma unroll
    for (int off = 1; off < 64; off <<= 1){
      int sh = __shfl_up(inc, off, 64);
      if (lane >= off) inc += sh;
    }
    if (lane == 63) wsum[wv] = (u32)inc;
    __syncthreads();
    int woff = 0;
    for (int k = 0; k < 4; ++k) if (k < wv) woff += (int)wsum[k];
    int run = woff + inc - st;
#pragma unroll
    for (int j = 0; j < 25; ++j){
      int i = base + j;
      run += vals[j];
      if (i < NARC) S16[i] = (short)run;
    }
  }
  __syncthreads();

  // --- C1: depth[v] = scan value at v's entry (down) arc ---
  if (t == 0) dep[0] = 0;
  for (int idx = t; idx < NL*4; idx += NT){
    int u = idx >> 2, sl = idx & 3;
    int v = (int)adjl4[idx];
    if (v != 0xffff){
      int a  = arcB[u] + sl;
      int rs = 0;
#pragma unroll
      for (int j = 0; j < 4; ++j) if ((int)adjl4[v*4+j] == u) rs = j;
      int ar = arcB[v] + rs;
      if (rankA[a] > rankA[ar]){
        int pt = (NARC - 1) - (int)rankA[a];
        dep[v] = (u16)S16[pt];
      }
    }
  }
  __syncthreads();

  // --- C2: parent[v] (over S16) ---
  if (t == 0) parA[0] = 0;
  for (int idx = t; idx < NL*4; idx += NT){
    int u = idx >> 2, sl = idx & 3;
    int v = (int)adjl4[idx];
    if (v != 0xffff){
      int a  = arcB[u] + sl;
      int rs = 0;
#pragma unroll
      for (int j = 0; j < 4; ++j) if ((int)adjl4[v*4+j] == u) rs = j;
      int ar = arcB[v] + rs;
      if (rankA[a] > rankA[ar]) parA[v] = (u16)u;
    }
  }
  __syncthreads();

  // --- D: level histogram + max depth (hist over rankA) ---
  for (int i = t; i < NL; i += NT) hist[i] = 0;
  __syncthreads();
  int mloc = 0;
  for (int v = t; v < NL; v += NT){
    int dv = (int)dep[v];
    atomicAdd(&hist[dv], 1u);
    if (dv > mloc) mloc = dv;
  }
#pragma unroll
  for (int off = 1; off < 64; off <<= 1){
    int o = __shfl_xor(mloc, off, 64);
    if (o > mloc) mloc = o;
  }
  __syncthreads();            // protect wsum reuse
  if (lane == 0) wsum[wv] = (u32)mloc;
  __syncthreads();
  int maxd = 0;
  for (int k = 0; k < 4; ++k){ int x = (int)wsum[k]; if (x > maxd) maxd = x; }
  int nlev = maxd + 1;
  __syncthreads();            // protect wsum for phase E scan

  // --- E: exclusive scan of hist -> level starts (in place); write lvl_g ---
  {
    int hloc[13]; int st = 0;
#pragma unroll
    for (int j = 0; j < 13; ++j){
      int i2 = t*13 + j;
      hloc[j] = (i2 < NL) ? (int)hist[i2] : 0;
      st += hloc[j];
    }
    int inc = st;
#pragma unroll
    for (int off = 1; off < 64; off <<= 1){
      int sh = __shfl_up(inc, off, 64);
      if (lane >= off) inc += sh;
    }
    if (lane == 63) wsum[wv] = (u32)inc;
    __syncthreads();
    int woff = 0;
    for (int k = 0; k < 4; ++k) if (k < wv) woff += (int)wsum[k];
    int run = woff + inc - st;
#pragma unroll
    for (int j = 0; j < 13; ++j){
      int i2 = t*13 + j;
      int h = hloc[j];
      if (i2 < NL) hist[i2] = (u32)run;   // exclusive prefix = level start
      run += h;
    }
  }
  __syncthreads();
  for (int i = t; i < nlev; i += NT) lvl_g[b*3200 + i] = (int)hist[i];
  if (t == 0){ lvl_g[b*3200 + nlev] = NL; nlev_g[b] = nlev; }
  __syncthreads();

  // --- F: scatter nodes to positions (hist doubles as per-level cursor) ---
  for (int v = t; v < NL; v += NT){
    u32 p = atomicAdd(&hist[(int)dep[v]], 1u);
    posA[v] = (u16)p;
  }
  __syncthreads();

  // --- G: final global writes ---
  for (int v = t; v < NL; v += NT){
    int p = (int)posA[v];
    order_g[b*NL + p] = v;
    pos_g[b*NL + v] = p;
    parpos_g[b*NL + p] = (int)posA[parA[v]];
  }
}

// ---------- in_proj GEMM body (BN=128, DUALOUT), LDS passed in ----------
__device__ void inproj_body(char* sm, int bid, const u16* __restrict__ Ap, const u16* __restrict__ Wp,
                            float* __restrict__ Cm, float* __restrict__ C2){
  const int K = 192, K2 = 384;
  short* Ah = (short*)sm;              // 128*64
  short* Wh = (short*)(sm + 16384);    // 128*64
  short* Wl = (short*)(sm + 32768);    // 128*64
  const int bn = (bid % 6) * 128, bm = (bid / 6) * 128;
  const int tid = threadIdx.x, lane = tid & 63, wid = tid >> 6;
  const int wr = wid >> 1, wc = wid & 1;
  f4 acc[4][4];
#pragma unroll
  for (int mf = 0; mf < 4; ++mf)
#pragma unroll
    for (int nf = 0; nf < 4; ++nf) acc[mf][nf] = (f4){0.f,0.f,0.f,0.f};

  for (int k0 = 0; k0 < K; k0 += 64){
#pragma unroll
    for (int j = 0; j < 4; ++j){
      int isb = wid*4 + j;
      int r = isb*8 + (lane >> 3);
      int c = lane & 7;
      const u16* src = Ap + (size_t)(bm + r) * K + k0 + ((c ^ (r & 7)) << 3);
      GL16(src, &Ah[isb*512]);
    }
#pragma unroll
    for (int j = 0; j < 4; ++j){
      int isb = wid*4 + j;
      int r = isb*8 + (lane >> 3);
      int c = lane & 7;
      const u16* src = Wp + (size_t)(bn + r) * K2 + k0 + ((c ^ (r & 7)) << 3);
      GL16(src,     &Wh[isb*512]);
      GL16(src + K, &Wl[isb*512]);
    }
    __syncthreads();
#pragma unroll
    for (int kk = 0; kk < 2; ++kk){
      bh8 whf[4], wlf[4], ahf[4];
#pragma unroll
      for (int nf = 0; nf < 4; ++nf){
        int rw = wc*64 + nf*16 + (lane & 15);
        int c = kk*4 + (lane >> 4);
        int ad = rw*64 + ((c ^ (rw & 7)) * 8);
        whf[nf] = *(const bh8*)&Wh[ad];
        wlf[nf] = *(const bh8*)&Wl[ad];
      }
#pragma unroll
      for (int mf = 0; mf < 4; ++mf){
        int ra = wr*64 + mf*16 + (lane & 15);
        int c = kk*4 + (lane >> 4);
        int ad = ra*64 + ((c ^ (ra & 7)) * 8);
        ahf[mf] = *(const bh8*)&Ah[ad];
      }
#pragma unroll
      for (int mf = 0; mf < 4; ++mf)
#pragma unroll
        for (int nf = 0; nf < 4; ++nf){
          acc[mf][nf] = __builtin_amdgcn_mfma_f32_16x16x32_bf16(ahf[mf], whf[nf], acc[mf][nf], 0, 0, 0);
          acc[mf][nf] = __builtin_amdgcn_mfma_f32_16x16x32_bf16(ahf[mf], wlf[nf], acc[mf][nf], 0, 0, 0);
        }
    }
    __syncthreads();
  }
  const int cb = bn + wc*64;
#pragma unroll
  for (int mf = 0; mf < 4; ++mf){
    int row = bm + wr*64 + mf*16 + (lane >> 4)*4;
#pragma unroll
    for (int nf = 0; nf < 4; ++nf){
      int col = cb + nf*16 + (lane & 15);
#pragma unroll
      for (int r = 0; r < 4; ++r){
        float v = acc[mf][nf][r];
        float* op = (col < 384) ? Cm : C2;
        int oc = (col < 384) ? col : col - 384;
        op[(size_t)(row + r) * 384 + oc] = v;
      }
    }
  }
}

// ---------- fused: blocks 0..7 = tree, blocks 8.. = in_proj GEMM ----------
__global__ __launch_bounds__(256) void fused_tree_inproj(
    const u64* __restrict__ keysg, int* __restrict__ ordg, int* __restrict__ ppg,
    int* __restrict__ posg, int* __restrict__ lvlg, int* __restrict__ nlvg,
    const u16* __restrict__ Ap, const u16* __restrict__ Wp,
    float* __restrict__ Cm, float* __restrict__ C2){
  __shared__ __align__(16) char sm[62736];
  int bid = blockIdx.x;
  if (bid < 8){
    tree_body(sm, bid, keysg, ordg, ppg, posg, lvlg, nlvg);
  } else {
    inproj_body(sm, bid - 8, Ap, Wp, Cm, C2);
  }
}

// ---------- fused: blocks 0..7 = window-schedule build, blocks 8.. = conv ----------
__global__ __launch_bounds__(256) void sched_conv_kernel(
    const int* __restrict__ lvl_g, const int* __restrict__ nlev_g,
    u32* __restrict__ wsched_g, int* __restrict__ nwin_g,
    const float* __restrict__ xs, const float* __restrict__ cw,
    const float* __restrict__ cb, float* __restrict__ u){
  __shared__ int lvls[3200];
  int bid = blockIdx.x;
  if (bid < 8){
    int b = bid;
    int tid = threadIdx.x;
    int d = nlev_g[b];
    for (int i = tid; i <= d; i += 256) lvls[i] = lvl_g[b*3200 + i];
    __syncthreads();
    if (tid >= 64) return;
    int lane = tid;
    u32* su = wsched_g + (size_t)b*6528;
    u32* sd = su + 3264;
    int nk = d - 1;
    for (int pass = 0; pass < 2; ++pass){
      u32* out = pass ? sd : su;
      int carry = 0;
      for (int c0 = 0; c0 < nk; c0 += 64){
        int kk = c0 + lane;
        bool valid = kk < nk;
        int lo = 0, hi = 0, wc = 0;
        if (valid){
          int dd = pass ? (1 + kk) : (d - 1 - kk);
          lo = lvls[dd]; hi = lvls[dd+1];
          wc = (hi - lo + 63) >> 6;
        }
        int inc = wc;
        for (int off = 1; off < 64; off <<= 1){
          int v = __shfl_up(inc, off, 64);
          if (lane >= off) inc += v;
        }
        int excl = carry + inc - wc;
        if (valid){
          for (int w = 0; w < wc; ++w){
            int base2 = lo + (w << 6);
            u32 e = (u32)base2 | ((u32)hi << 16);
            if (base2 + 64 >= hi) e |= 0x80000000u;
            out[excl + w] = e;
          }
        }
        carry += __shfl(inc, 63, 64);
      }
      if (lane == 0) nwin_g[b*2 + pass] = carry;
    }
  } else {
    int idx = (bid - 8) * 256 + threadIdx.x;
    if (idx >= ROWS * 96) return;
    int q = idx % 96; int l = idx / 96;
    int b = l / NL; int hw = l - b * NL; int h = hw / 56; int wcc = hw - h * 56;
    int c4 = q * 4;
    float4 acc = *(const float4*)(cb + c4);
#pragma unroll
    for (int kh = 0; kh < 3; ++kh){
      int hh = h + kh - 1; if (hh < 0 || hh >= 56) continue;
#pragma unroll
      for (int kw = 0; kw < 3; ++kw){
        int wwc = wcc + kw - 1; if (wwc < 0 || wwc >= 56) continue;
        float4 iv = *(const float4*)(xs + ((size_t)(b * NL + hh*56 + wwc)) * DIN + c4);
        float4 wv = *(const float4*)(cw + (size_t)(kh*3 + kw) * DIN + c4);
        acc.x += iv.x * wv.x; acc.y += iv.y * wv.y; acc.z += iv.z * wv.z; acc.w += iv.w * wv.w;
      }
    }
    float4 o; o.x = siluf(acc.x); o.y = siluf(acc.y); o.z = siluf(acc.z); o.w = siluf(acc.w);
    *(float4*)(u + (size_t)l * DIN + c4) = o;
  }
}

// ---------- layernorm (wave per row); BF16OUT -> plain bf16 row ----------
template<int D, bool BF16OUT>
__global__ __launch_bounds__(256) void ln_kernel(const float* __restrict__ in, const float* __restrict__ g,
                                                 const float* __restrict__ bt, void* __restrict__ outv){
  int gw = (int)((blockIdx.x * 256u + threadIdx.x) >> 6);
  int lane = threadIdx.x & 63;
  if (gw >= ROWS) return;
  constexpr int J = D / 64;
  const float* r = in + (size_t)gw * D;
  float v[J]; float s = 0.f;
#pragma unroll
  for (int j = 0; j < J; ++j){ v[j] = r[lane + 64*j]; s += v[j]; }
  s = wredsum(s);
  float mu = s * (1.0f / D);
  float q = 0.f;
#pragma unroll
  for (int j = 0; j < J; ++j){ float dd = v[j] - mu; q += dd*dd; }
  q = wredsum(q);
  float rs = rsqrtf(q * (1.0f / D) + 1e-5f);
  if (BF16OUT){
    u16* o = (u16*)outv + (size_t)gw * D;
#pragma unroll
    for (int j = 0; j < J; ++j){
      int dch = lane + 64*j;
      float y = (v[j] - mu) * rs * g[dch] + bt[dch];
      o[dch] = f2bf(y);
    }
  } else {
    float* o = (float*)outv + (size_t)gw * D;
#pragma unroll
    for (int j = 0; j < J; ++j){ int dch = lane + 64*j; o[dch] = (v[j] - mu) * rs * g[dch] + bt[dch]; }
  }
}

// ---------- MFMA GEMM: A plain bf16 [M,K]; W split hi|lo [N,2K]. ----------
template<int BN, bool BIAS, int ACT, bool RESID, bool OBF16, bool DUALOUT>
__global__ __launch_bounds__(256) void mgemm_kernel(
    const u16* __restrict__ Ap, const u16* __restrict__ Wp,
    const float* __restrict__ bias, const float* __restrict__ resid,
    float* __restrict__ Cm, float* __restrict__ C2, int M, int N, int K){
  static_assert(BN == 64 || BN == 128, "BN");
  constexpr int WT = (BN == 128) ? 64 : 32;
  constexpr int NF = WT / 16;
  __shared__ short Ah[128*64];
  __shared__ short Wh[BN*64], Wl[BN*64];
  const int bm = blockIdx.y * 128, bn = blockIdx.x * BN;
  const int tid = threadIdx.x, lane = tid & 63, wid = tid >> 6;
  const int wr = wid >> 1, wc = wid & 1;
  const int K2 = 2 * K;
  f4 acc[4][NF];
#pragma unroll
  for (int mf = 0; mf < 4; ++mf)
#pragma unroll
    for (int nf = 0; nf < NF; ++nf) acc[mf][nf] = (f4){0.f,0.f,0.f,0.f};

  for (int k0 = 0; k0 < K; k0 += 64){
#pragma unroll
    for (int j = 0; j < 4; ++j){
      int isb = wid*4 + j;
      int r = isb*8 + (lane >> 3);
      int c = lane & 7;
      const u16* src = Ap + (size_t)(bm + r) * K + k0 + ((c ^ (r & 7)) << 3);
      GL16(src, &Ah[isb*512]);
    }
#pragma unroll
    for (int j = 0; j < BN/32; ++j){
      int isb = wid*(BN/32) + j;
      int r = isb*8 + (lane >> 3);
      int c = lane & 7;
      const u16* src = Wp + (size_t)(bn + r) * K2 + k0 + ((c ^ (r & 7)) << 3);
      GL16(src,     &Wh[isb*512]);
      GL16(src + K, &Wl[isb*512]);
    }
    __syncthreads();
#pragma unroll
    for (int kk = 0; kk < 2; ++kk){
      bh8 whf[NF], wlf[NF], ahf[4];
#pragma unroll
      for (int nf = 0; nf < NF; ++nf){
        int rw = wc*WT + nf*16 + (lane & 15);
        int c = kk*4 + (lane >> 4);
        int ad = rw*64 + ((c ^ (rw & 7)) * 8);
        whf[nf] = *(const bh8*)&Wh[ad];
        wlf[nf] = *(const bh8*)&Wl[ad];
      }
#pragma unroll
      for (int mf = 0; mf < 4; ++mf){
        int ra = wr*64 + mf*16 + (lane & 15);
        int c = kk*4 + (lane >> 4);
        int ad = ra*64 + ((c ^ (ra & 7)) * 8);
        ahf[mf] = *(const bh8*)&Ah[ad];
      }
#pragma unroll
      for (int mf = 0; mf < 4; ++mf)
#pragma unroll
        for (int nf = 0; nf < NF; ++nf){
          acc[mf][nf] = __builtin_amdgcn_mfma_f32_16x16x32_bf16(ahf[mf], whf[nf], acc[mf][nf], 0, 0, 0);
          acc[mf][nf] = __builtin_amdgcn_mfma_f32_16x16x32_bf16(ahf[mf], wlf[nf], acc[mf][nf], 0, 0, 0);
        }
    }
    __syncthreads();
  }
  const int cb = bn + wc*WT;
#pragma unroll
  for (int mf = 0; mf < 4; ++mf){
    int row = bm + wr*64 + mf*16 + (lane >> 4)*4;
#pragma unroll
    for (int nf = 0; nf < NF; ++nf){
      int col = cb + nf*16 + (lane & 15);
#pragma unroll
      for (int r = 0; r < 4; ++r){
        float v = acc[mf][nf][r];
        if (BIAS) v += bias[col];
        if (ACT == 1) v = geluf(v);
        if (RESID) v += resid[(size_t)(row + r) * N + col];
        if (DUALOUT){
          float* op = (col < 384) ? Cm : C2;
          int oc = (col < 384) ? col : col - 384;
          op[(size_t)(row + r) * 384 + oc] = v;
        } else if (OBF16){
          u16* op = (u16*)Cm;
          op[(size_t)(row + r) * N + col] = f2bf(v);
        } else {
          Cm[(size_t)(row + r) * N + col] = v;
        }
      }
    }
  }
}

// ---------- x_proj + dt_proj + softplus + w/feat (wave per row), BFS-pos output ----------
__global__ __launch_bounds__(256) void xdbl_kernel(const float* __restrict__ u,
    const float* __restrict__ xpw, const float* __restrict__ dtw_g,
    const float* __restrict__ dtb, const float* __restrict__ alog, const int* __restrict__ pos_g,
    float* __restrict__ wout, float* __restrict__ fout, float* __restrict__ csout){
  __shared__ float xw[14*384];
  __shared__ float dw[384*12];
  __shared__ float db[384];
  __shared__ float An[384];
  int t = threadIdx.x;
  for (int i = t; i < 14*384; i += 256) xw[i] = xpw[i];
  for (int i = t; i < 384*12; i += 256) dw[i] = dtw_g[i];
  for (int i = t; i < 384; i += 256){ db[i] = dtb[i]; An[i] = -expf(alog[i]); }
  __syncthreads();
  int wave = t >> 6, lane = t & 63;
  int row0 = blockIdx.x * 16 + wave * 4;
  for (int rr = 0; rr < 4; ++rr){
    int m = row0 + rr;
    int b = m / NL;
    int pos = pos_g[m];
    size_t orow = ((size_t)b * NL + pos) * DIN;
    const float* ur = u + (size_t)m * DIN;
    float u6[6];
#pragma unroll
    for (int j = 0; j < 6; ++j) u6[j] = ur[lane + 64*j];
    float xd[14];
#pragma unroll
    for (int r = 0; r < 14; ++r){
      float p = 0.f;
#pragma unroll
      for (int j = 0; j < 6; ++j) p += u6[j] * xw[r*384 + lane + 64*j];
      xd[r] = wredsum(p);
    }
    float Bs = xd[12], Cv = xd[13];
#pragma unroll
    for (int j = 0; j < 6; ++j){
      int dch = lane + 64*j;
      float pre = db[dch];
#pragma unroll
      for (int r = 0; r < 12; ++r) pre += xd[r] * dw[dch*12 + r];
      float dts = sofplus(pre);
      float wv = expf(dts * An[dch]);
      float fv = dts * Bs * u6[j];
      wout[orow + dch] = wv;
      fout[orow + dch] = fv;
    }
    if (lane == 0) csout[m] = Cv;
  }
}

// ---------- w transpose: [b][pos][384] -> planar [b][ch][pos] (64x64 LDS tiles) ----------
__global__ __launch_bounds__(256) void wtr_kernel(const float* __restrict__ in, float* __restrict__ out){
  __shared__ float tile[64][65];
  int blk = blockIdx.x;
  int b = blk / (49*6);
  int r = blk - b*(49*6);
  int pt = r / 6, ct = r - pt*6;
  int t = threadIdx.x;
  int tr = t >> 6, lane = t & 63;
  const float* src = in + ((size_t)b*NL + (size_t)pt*64) * DIN + ct*64;
#pragma unroll
  for (int k = 0; k < 16; ++k){
    int rr = tr + k*4;
    tile[rr][lane] = src[(size_t)rr*DIN + lane];
  }
  __syncthreads();
  float* dst = out + ((size_t)b*DIN + (size_t)ct*64) * NL + (size_t)pt*64;
#pragma unroll
  for (int k = 0; k < 16; ++k){
    int cc = tr + k*4;
    dst[(size_t)cc*NL + lane] = tile[lane][cc];
  }
}

// ---------- sweep8: flat window schedule + depth-2 w/pp prefetch. ----------
template<bool UP>
__device__ __forceinline__ void sweep_run(const u32* __restrict__ sc, int nw,
    float* __restrict__ Sp, const float* __restrict__ wbase, const int* __restrict__ pg, int lane){
  if (nw <= 0) return;
  u32 d0 = sc[lane];
  u32 d1 = sc[64 + lane];
  int curch = 0;
  float wA = 0.f, wB = 0.f; int pA = 0, pB = 0;
  int baseA = 0, hiA = 0, baseB = 0, hiB = 0;
  u32 eA = 0, eB = 0; bool aA = false, aB = false;
  {
    u32 dc = __shfl(d0, 0, 64);
    baseA = (int)(dc & 0xffffu); hiA = (int)((dc >> 16) & 0x7fffu); eA = dc >> 31;
    int p = baseA + lane; aA = p < hiA;
    if (aA){ wA = wbase[p]; pA = pg[p]; }
  }
  if (nw > 1){
    u32 dc = __shfl(d0, 1, 64);
    baseB = (int)(dc & 0xffffu); hiB = (int)((dc >> 16) & 0x7fffu); eB = dc >> 31;
    int p = baseB + lane; aB = p < hiB;
    if (aB){ wB = wbase[p]; pB = pg[p]; }
  }
  for (int iw = 0; iw < nw; ++iw){
    int ch = iw >> 6;
    if (ch != curch){ d0 = d1; d1 = sc[(ch + 1)*64 + lane]; curch = ch; }
    float wN = 0.f; int pN = 0; int baseN = 0, hiN = 0; u32 eN = 0; bool aN = false;
    int iw2 = iw + 2;
    if (iw2 < nw){
      int ch2 = iw2 >> 6;
      u32 dc2 = __shfl((ch2 == curch) ? d0 : d1, iw2 & 63, 64);
      baseN = (int)(dc2 & 0xffffu); hiN = (int)((dc2 >> 16) & 0x7fffu); eN = dc2 >> 31;
      int p = baseN + lane; aN = p < hiN;
      if (aN){ wN = wbase[p]; pN = pg[p]; }
    }
    int p = baseA + lane;
    if (aA){
      if (UP){
        float s = Sp[p];
        atomicAdd(&Sp[pA], wA * s);
      } else {
        float s = Sp[p]; float h = Sp[pA];
        Sp[p] = s + wA * (h - wA * s);
      }
    }
    if (eA){
      asm volatile("s_waitcnt lgkmcnt(0)" ::: "memory");
    }
    baseA = baseB; hiA = hiB; aA = aB; wA = wB; pA = pB; eA = eB;
    baseB = baseN; hiB = hiN; aB = aN; wB = wN; pB = pN; eB = eN;
  }
}

__global__ __launch_bounds__(256) void sweep8_kernel(const float* __restrict__ featp, const float* __restrict__ wtr,
    float* __restrict__ Hp, const int* __restrict__ parpos_g,
    const u32* __restrict__ wsched_g, const int* __restrict__ nwin_g){
  __shared__ float S[4*NL];    // 50176B -> 3 blocks/CU
  int blk = blockIdx.x;
  int b = blk & 7, q = blk >> 3;   // tree b pinned to XCD b
  int t = threadIdx.x, lane = t & 63, wv = t >> 6;
  const int* pg = parpos_g + b*NL;
  const float* fbase = featp + (size_t)b*NL*DIN + q*4;
  const float* wbase = wtr + ((size_t)b*DIN + q*4 + wv) * NL;
  float*       hbase = Hp    + (size_t)b*NL*DIN + q*4;
  for (int i = t; i < NL; i += 256){
    float4 f = *(const float4*)(fbase + (size_t)i*DIN);
    S[0*NL + i] = f.x; S[1*NL + i] = f.y; S[2*NL + i] = f.z; S[3*NL + i] = f.w;
  }
  __syncthreads();
  float* Sp = &S[wv*NL];

  const u32* su = wsched_g + (size_t)b*6528;
  const u32* sd = su + 3264;
  int nwu = nwin_g[b*2], nwd = nwin_g[b*2 + 1];
  sweep_run<true>(su, nwu, Sp, wbase, pg, lane);
  sweep_run<false>(sd, nwd, Sp, wbase, pg, lane);

  __syncthreads();
  for (int i = t; i < NL; i += 256){
    float4 o;
    o.x = S[0*NL + i]; o.y = S[1*NL + i]; o.z = S[2*NL + i]; o.w = S[3*NL + i];
    *(float4*)(hbase + (size_t)i*DIN) = o;
  }
}

// ---------- y = Cs*H + Ds*u -> LN -> * silu(z) -> plain bf16 (pos-row input) ----------
__global__ __launch_bounds__(256) void ynorm_kernel(const float* __restrict__ Hp, const float* __restrict__ u,
    const float* __restrict__ z, const float* __restrict__ Cs, const int* __restrict__ order_g,
    const float* __restrict__ Ds, const float* __restrict__ g, const float* __restrict__ bt,
    u16* __restrict__ out){
  int gw = (int)((blockIdx.x * 256u + threadIdx.x) >> 6);   // pos-row
  int lane = threadIdx.x & 63;
  if (gw >= ROWS) return;
  int b = gw / NL;
  int node = order_g[gw];
  size_t nrow = (size_t)b * NL + node;
  float Cv = Cs[nrow];
  const float* hr = Hp + (size_t)gw * DIN;
  const float* ur = u + nrow * DIN;
  const float* zr = z + nrow * DIN;
  float y[6]; float s = 0.f;
#pragma unroll
  for (int j = 0; j < 6; ++j){
    int dch = lane + 64*j;
    y[j] = Cv * hr[dch] + Ds[dch] * ur[dch];
    s += y[j];
  }
  s = wredsum(s);
  float mu = s * (1.0f / DIN);
  float q = 0.f;
#pragma unroll
  for (int j = 0; j < 6; ++j){ float dd = y[j] - mu; q += dd*dd; }
  q = wredsum(q);
  float rs = rsqrtf(q * (1.0f / DIN) + 1e-5f);
  u16* o = out + nrow * DIN;
#pragma unroll
  for (int j = 0; j < 6; ++j){
    int dch = lane + 64*j;
    float yn = (y[j] - mu) * rs * g[dch] + bt[dch];
    float v = yn * siluf(zr[dch]);
    o[dch] = f2bf(v);
  }
}

// ---------- host orchestration ----------
extern "C" void kernel_launch(void* const* d_in, const int* in_sizes, int n_in,
                              void* d_out, int out_size, void* d_ws, size_t ws_size,
                              hipStream_t stream){
  const float* x_in       = (const float*)d_in[0];
  const float* norm1_w    = (const float*)d_in[1];
  const float* norm1_b    = (const float*)d_in[2];
  const float* in_proj_w  = (const float*)d_in[3];
  const float* conv_w     = (const float*)d_in[4];
  const float* conv_b     = (const float*)d_in[5];
  const float* x_proj_w   = (const float*)d_in[6];
  const float* dt_proj_w  = (const float*)d_in[7];
  const float* dt_proj_b  = (const float*)d_in[8];
  const float* A_log      = (const float*)d_in[9];
  const float* Ds         = (const float*)d_in[10];
  const float* out_norm_w = (const float*)d_in[11];
  const float* out_norm_b = (const float*)d_in[12];
  const float* out_proj_w = (const float*)d_in[13];
  const float* norm2_w    = (const float*)d_in[14];
  const float* norm2_b    = (const float*)d_in[15];
  const float* fc1_w      = (const float*)d_in[16];
  const float* fc1_b      = (const float*)d_in[17];
  const float* fc2_w      = (const float*)d_in[18];
  const float* fc2_b      = (const float*)d_in[19];
  const float* fnorm_w    = (const float*)d_in[20];
  const float* fnorm_b    = (const float*)d_in[21];

  float* ws = (float*)d_ws;
  float* X     = ws + 0;
  u16*   bufAh = (u16*)(ws + 4816896);
  float* bufZ  = ws + 9633792;
  float* bufW  = ws + 19267584;
  float* bufU  = ws + 28901376;
  float* bufF  = ws + 38535168;
  u16*   Gp    = (u16*)bufU;
  float* Csb   = ws + 48168960;
  int*   ordg  = (int*)(ws + 48194048);
  int*   ppg   = (int*)(ws + 48219136);
  int*   lvlg  = (int*)(ws + 48244224);
  int*   nlvg  = (int*)(ws + 48269824);
  u64*   keysg = (u64*)(ws + 48269832);
  u16*   ipWp  = (u16*)(ws + 48393480);
  u16*   opWp  = (u16*)(ws + 48540936);
  u16*   fc1Wp = (u16*)(ws + 48614664);
  u16*   fc2Wp = (u16*)(ws + 48762120);
  int*   posg  = (int*)(ws + 48909576);
  float* wtrp  = ws + 48934664;          // planar w [b][384][NL]
  u32*   wschg = (u32*)(ws + 58568456);  // 8*6528 u32
  int*   nwing = (int*)(ws + 58620680);  // 16 ints

  hipMemcpyAsync(X, x_in, (size_t)ROWS * NC * sizeof(float), hipMemcpyDeviceToDevice, stream);

  for (int i = 0; i < 2; ++i){
    // ln1 (0..6271) || keys (6272..18591) || wprep (18592..20607)
    keysln_kernel<<<20608, 256, 0, stream>>>(X, norm1_w + i*NC, norm1_b + i*NC, bufAh, keysg,
                                             in_proj_w + (size_t)i*NHID*NC, out_proj_w + (size_t)i*NC*DIN,
                                             fc1_w + (size_t)i*NHID*NC, fc2_w + (size_t)i*NC*NHID,
                                             ipWp, opWp, fc1Wp, fc2Wp);

    // fused: tree (blocks 0..7) + in_proj GEMM (blocks 8..1183)
    fused_tree_inproj<<<8 + 6*196, 256, 0, stream>>>(keysg, ordg, ppg, posg, lvlg, nlvg,
                                                     bufAh, ipWp, bufF, bufZ);

    // sched (blocks 0..7) || conv (blocks 8..9415)
    sched_conv_kernel<<<8 + (ROWS*96)/256, 256, 0, stream>>>(lvlg, nlvg, wschg, nwing,
                                                             bufF, conv_w + (size_t)i*9*DIN, conv_b + i*DIN, bufU);

    xdbl_kernel<<<ROWS/16, 256, 0, stream>>>(bufU, x_proj_w + (size_t)i*14*DIN, dt_proj_w + (size_t)i*DIN*12,
                                             dt_proj_b + i*DIN, A_log + i*DIN, posg, bufW, bufF, Csb);

    wtr_kernel<<<8*49*6, 256, 0, stream>>>(bufW, wtrp);

    sweep8_kernel<<<NB*96, 256, 0, stream>>>(bufF, wtrp, bufF, ppg, wschg, nwing);

    ynorm_kernel<<<ROWS/4, 256, 0, stream>>>(bufF, bufU, bufZ, Csb, ordg, Ds + i*DIN,
                                             out_norm_w + i*DIN, out_norm_b + i*DIN, (u16*)bufW);

    mgemm_kernel<64,false,0,true,false,false><<<dim3(3,196), 256, 0, stream>>>((u16*)bufW, opWp, nullptr, X, X, nullptr, ROWS, 192, 384);

    ln_kernel<192,true><<<ROWS/4, 256, 0, stream>>>(X, norm2_w + i*NC, norm2_b + i*NC, bufAh);
    mgemm_kernel<128,true,1,false,true,false><<<dim3(6,196), 256, 0, stream>>>(bufAh, fc1Wp, fc1_b + i*NHID, nullptr, (float*)Gp, nullptr, ROWS, NHID, 192);
    mgemm_kernel<64,true,0,true,false,false><<<dim3(3,196), 256, 0, stream>>>(Gp, fc2Wp, fc2_b + i*NC, X, X, nullptr, ROWS, 192, 768);
  }

  ln_kernel<192,false><<<ROWS/4, 256, 0, stream>>>(X, fnorm_w, fnorm_b, d_out);
}